// Round 1
// baseline (438.109 us; speedup 1.0000x reference)
//
#include <hip/hip_runtime.h>

#define N_TOK 4096
#define E_DIM 1024
#define NH    16
#define HD    64

typedef __bf16 bf16x8 __attribute__((ext_vector_type(8)));
typedef float  f32x4  __attribute__((ext_vector_type(4)));

// ---------- 16-element loaders (global -> two bf16x8), with fp32->bf16 convert ----------
__device__ __forceinline__ void load16(const float* __restrict__ p, bf16x8& lo, bf16x8& hi) {
    float4 f0 = ((const float4*)p)[0];
    float4 f1 = ((const float4*)p)[1];
    float4 f2 = ((const float4*)p)[2];
    float4 f3 = ((const float4*)p)[3];
    lo = bf16x8{(__bf16)f0.x, (__bf16)f0.y, (__bf16)f0.z, (__bf16)f0.w,
                (__bf16)f1.x, (__bf16)f1.y, (__bf16)f1.z, (__bf16)f1.w};
    hi = bf16x8{(__bf16)f2.x, (__bf16)f2.y, (__bf16)f2.z, (__bf16)f2.w,
                (__bf16)f3.x, (__bf16)f3.y, (__bf16)f3.z, (__bf16)f3.w};
}
__device__ __forceinline__ void load16(const __bf16* __restrict__ p, bf16x8& lo, bf16x8& hi) {
    lo = *(const bf16x8*)p;
    hi = *(const bf16x8*)(p + 8);
}

// ---------- shared GEMM core: C[128x128] tile, out[n][f] = sum_k A[n][k]*B[f][k] ----------
// 256 threads = 4 waves in 2x2; each wave computes 64x64 = 4x4 mfma frags.
#define LDSTR 40   // 32 + 8 pad (bf16 elems)

template <typename TA, typename TB>
__device__ __forceinline__ void gemm_core(const TA* __restrict__ A, const TB* __restrict__ B,
                                          const int K, const int rowBase, const int colBase,
                                          __bf16* As, __bf16* Bs, f32x4 (&acc)[4][4]) {
    const int tid  = threadIdx.x;
    const int lane = tid & 63;
    const int wid  = tid >> 6;
    const int wm = wid >> 1, wn = wid & 1;
    const int lr = lane & 15, lg = lane >> 4;
    const int srow = tid >> 1;            // 0..127
    const int shalf = (tid & 1) * 16;     // 0 or 16 (k offset)

    for (int kt = 0; kt < K; kt += 32) {
        bf16x8 alo, ahi, blo, bhi;
        load16(A + (size_t)(rowBase + srow) * K + kt + shalf, alo, ahi);
        load16(B + (size_t)(colBase + srow) * K + kt + shalf, blo, bhi);
        __syncthreads();   // readers of previous tile done
        *(bf16x8*)&As[srow * LDSTR + shalf]     = alo;
        *(bf16x8*)&As[srow * LDSTR + shalf + 8] = ahi;
        *(bf16x8*)&Bs[srow * LDSTR + shalf]     = blo;
        *(bf16x8*)&Bs[srow * LDSTR + shalf + 8] = bhi;
        __syncthreads();   // tile visible

        bf16x8 af[4], bfr[4];
#pragma unroll
        for (int i = 0; i < 4; ++i) {
            af[i]  = *(const bf16x8*)&As[(wm * 64 + i * 16 + lr) * LDSTR + lg * 8];
            bfr[i] = *(const bf16x8*)&Bs[(wn * 64 + i * 16 + lr) * LDSTR + lg * 8];
        }
#pragma unroll
        for (int i = 0; i < 4; ++i)
#pragma unroll
            for (int j = 0; j < 4; ++j)
                acc[i][j] = __builtin_amdgcn_mfma_f32_16x16x32_bf16(af[i], bfr[j], acc[i][j], 0, 0, 0);
    }
}

// ---------- kernel 1: QKV projection, scatter to per-head bf16 Q/K/V ----------
__global__ __launch_bounds__(256) void qkv_gemm(const float* __restrict__ x,
                                                const float* __restrict__ wqkv,
                                                const float* __restrict__ bqkv,
                                                __bf16* __restrict__ Qb,
                                                __bf16* __restrict__ Kb,
                                                __bf16* __restrict__ Vb) {
    __shared__ __bf16 As[128 * LDSTR];
    __shared__ __bf16 Bs[128 * LDSTR];
    f32x4 acc[4][4];
#pragma unroll
    for (int i = 0; i < 4; ++i)
#pragma unroll
        for (int j = 0; j < 4; ++j)
            acc[i][j] = f32x4{0.f, 0.f, 0.f, 0.f};

    const int tm = blockIdx.x, tn = blockIdx.y;
    gemm_core(x, wqkv, E_DIM, tm * 128, tn * 128, As, Bs, acc);

    const int tid = threadIdx.x;
    const int lane = tid & 63, wid = tid >> 6;
    const int wm = wid >> 1, wn = wid & 1;
    const int lr = lane & 15, lg = lane >> 4;

#pragma unroll
    for (int ni = 0; ni < 4; ++ni) {
        const int f = tn * 128 + wn * 64 + ni * 16 + lr;   // 0..3071
        const float bias = bqkv[f];
        const int which = f >> 10;          // 0=Q 1=K 2=V
        const int hh = (f & 1023) >> 6;
        const int dd = f & 63;
        __bf16* dst = (which == 0) ? Qb : (which == 1) ? Kb : Vb;
        const float sc = (which == 0) ? 0.125f : 1.0f;     // fold softmax scale into Q (exact pow2)
#pragma unroll
        for (int mi = 0; mi < 4; ++mi) {
#pragma unroll
            for (int r = 0; r < 4; ++r) {
                const int n = tm * 128 + wm * 64 + mi * 16 + lg * 4 + r;
                const float v = (acc[mi][ni][r] + bias) * sc;
                dst[((size_t)hh * N_TOK + n) * HD + dd] = (__bf16)v;
            }
        }
    }
}

// ---------- kernel 2: flash attention ----------
// grid (64 qblocks, 16 heads), 256 threads = 4 waves, each wave owns 16 q-rows.
#define KVB   64
#define FLSTR 72   // 64 + 8 pad

__global__ __launch_bounds__(256) void flash_attn(const __bf16* __restrict__ Qb,
                                                  const __bf16* __restrict__ Kb,
                                                  const __bf16* __restrict__ Vb,
                                                  __bf16* __restrict__ Ob) {
    __shared__ __bf16 Ks[KVB * FLSTR];
    __shared__ __bf16 Vt[HD * FLSTR];         // transposed: [d][kv]
    __shared__ __bf16 Ps[4][16 * FLSTR];      // per-wave P tile [16 rows][64 kv]

    const int qblk = blockIdx.x, h = blockIdx.y;
    const int tid = threadIdx.x, lane = tid & 63, wid = tid >> 6;
    const int lr = lane & 15, lg = lane >> 4;

    const __bf16* Qh = Qb + (size_t)h * N_TOK * HD;
    const __bf16* Kh = Kb + (size_t)h * N_TOK * HD;
    const __bf16* Vh = Vb + (size_t)h * N_TOK * HD;

    // Q frags for this wave's 16 rows (A-frag: row = lr, k(d) = kc*32 + lg*8 + j)
    const int qrow = qblk * 64 + wid * 16 + lr;
    bf16x8 qf[2];
    qf[0] = *(const bf16x8*)&Qh[(size_t)qrow * HD + lg * 8];
    qf[1] = *(const bf16x8*)&Qh[(size_t)qrow * HD + 32 + lg * 8];

    f32x4 o[4];
#pragma unroll
    for (int i = 0; i < 4; ++i) o[i] = f32x4{0.f, 0.f, 0.f, 0.f};
    float m[4] = {-INFINITY, -INFINITY, -INFINITY, -INFINITY};
    float l[4] = {0.f, 0.f, 0.f, 0.f};

    for (int kv0 = 0; kv0 < N_TOK; kv0 += KVB) {
        __syncthreads();   // previous tile's readers done
        {   // stage K rows: 4 threads/row, 16 bf16 each
            const int r = tid >> 2, seg = (tid & 3) * 16;
            bf16x8 klo, khi;
            load16(&Kh[(size_t)(kv0 + r) * HD + seg], klo, khi);
            *(bf16x8*)&Ks[r * FLSTR + seg]     = klo;
            *(bf16x8*)&Ks[r * FLSTR + seg + 8] = khi;
            // stage V transposed: 8 threads/row, each 8 elems, 2 rows per thread
            const int kvr = tid >> 3, d0 = (tid & 7) * 8;
#pragma unroll
            for (int half = 0; half < 2; ++half) {
                const int rr = kvr + half * 32;
                bf16x8 vv = *(const bf16x8*)&Vh[(size_t)(kv0 + rr) * HD + d0];
#pragma unroll
                for (int j = 0; j < 8; ++j) Vt[(d0 + j) * FLSTR + rr] = vv[j];
            }
        }
        __syncthreads();

        // S = Q K^T  (scale pre-folded into Q). s[cb]: cols cb*16+lr, rows lg*4+r
        f32x4 s[4];
#pragma unroll
        for (int cb = 0; cb < 4; ++cb) {
            f32x4 a = f32x4{0.f, 0.f, 0.f, 0.f};
#pragma unroll
            for (int kc = 0; kc < 2; ++kc) {
                bf16x8 kf = *(const bf16x8*)&Ks[(cb * 16 + lr) * FLSTR + kc * 32 + lg * 8];
                a = __builtin_amdgcn_mfma_f32_16x16x32_bf16(qf[kc], kf, a, 0, 0, 0);
            }
            s[cb] = a;
        }

        // online softmax per row (rows lg*4+r; 16 lanes of same lg share the row)
#pragma unroll
        for (int r = 0; r < 4; ++r) {
            float mx = fmaxf(fmaxf(s[0][r], s[1][r]), fmaxf(s[2][r], s[3][r]));
            mx = fmaxf(mx, __shfl_xor(mx, 1));
            mx = fmaxf(mx, __shfl_xor(mx, 2));
            mx = fmaxf(mx, __shfl_xor(mx, 4));
            mx = fmaxf(mx, __shfl_xor(mx, 8));
            const float mn = fmaxf(m[r], mx);
            const float alpha = __expf(m[r] - mn);
            float ps = 0.f;
#pragma unroll
            for (int cb = 0; cb < 4; ++cb) {
                const float p = __expf(s[cb][r] - mn);
                ps += p;
                Ps[wid][(lg * 4 + r) * FLSTR + cb * 16 + lr] = (__bf16)p;
            }
            ps += __shfl_xor(ps, 1);
            ps += __shfl_xor(ps, 2);
            ps += __shfl_xor(ps, 4);
            ps += __shfl_xor(ps, 8);
            l[r] = l[r] * alpha + ps;
            m[r] = mn;
            o[0][r] *= alpha; o[1][r] *= alpha; o[2][r] *= alpha; o[3][r] *= alpha;
        }

        // O += P V   (A-frag of P: row=lr, k(kv)=kc*32+lg*8+j; B-frag of V from Vt)
#pragma unroll
        for (int db = 0; db < 4; ++db) {
#pragma unroll
            for (int kc = 0; kc < 2; ++kc) {
                bf16x8 pf = *(const bf16x8*)&Ps[wid][lr * FLSTR + kc * 32 + lg * 8];
                bf16x8 vf = *(const bf16x8*)&Vt[(db * 16 + lr) * FLSTR + kc * 32 + lg * 8];
                o[db] = __builtin_amdgcn_mfma_f32_16x16x32_bf16(pf, vf, o[db], 0, 0, 0);
            }
        }
    }

    // epilogue: normalize and store bf16 [N][E]
#pragma unroll
    for (int db = 0; db < 4; ++db) {
#pragma unroll
        for (int r = 0; r < 4; ++r) {
            const int n = qblk * 64 + wid * 16 + lg * 4 + r;
            const int c = h * HD + db * 16 + lr;
            Ob[(size_t)n * E_DIM + c] = (__bf16)(o[db][r] / l[r]);
        }
    }
}

// ---------- kernel 3: output projection ----------
__global__ __launch_bounds__(256) void proj_gemm(const __bf16* __restrict__ Ob,
                                                 const float* __restrict__ wp,
                                                 const float* __restrict__ bp,
                                                 float* __restrict__ out) {
    __shared__ __bf16 As[128 * LDSTR];
    __shared__ __bf16 Bs[128 * LDSTR];
    f32x4 acc[4][4];
#pragma unroll
    for (int i = 0; i < 4; ++i)
#pragma unroll
        for (int j = 0; j < 4; ++j)
            acc[i][j] = f32x4{0.f, 0.f, 0.f, 0.f};

    const int tm = blockIdx.x, tn = blockIdx.y;
    gemm_core(Ob, wp, E_DIM, tm * 128, tn * 128, As, Bs, acc);

    const int tid = threadIdx.x;
    const int lane = tid & 63, wid = tid >> 6;
    const int wm = wid >> 1, wn = wid & 1;
    const int lr = lane & 15, lg = lane >> 4;

#pragma unroll
    for (int ni = 0; ni < 4; ++ni) {
        const int f = tn * 128 + wn * 64 + ni * 16 + lr;
        const float bias = bp[f];
#pragma unroll
        for (int mi = 0; mi < 4; ++mi) {
#pragma unroll
            for (int r = 0; r < 4; ++r) {
                const int n = tm * 128 + wm * 64 + mi * 16 + lg * 4 + r;
                out[(size_t)n * E_DIM + f] = acc[mi][ni][r] + bias;
            }
        }
    }
}

// ---------- launch ----------
extern "C" void kernel_launch(void* const* d_in, const int* in_sizes, int n_in,
                              void* d_out, int out_size, void* d_ws, size_t ws_size,
                              hipStream_t stream) {
    const float* x     = (const float*)d_in[0];
    const float* wqkv  = (const float*)d_in[1];
    const float* bqkv  = (const float*)d_in[2];
    const float* wproj = (const float*)d_in[3];
    const float* bproj = (const float*)d_in[4];
    float* out = (float*)d_out;

    const size_t headElems = (size_t)NH * N_TOK * HD;   // 4M elems
    __bf16* Qb = (__bf16*)d_ws;
    __bf16* Kb = Qb + headElems;
    __bf16* Vb = Kb + headElems;
    __bf16* Ob = Vb + headElems;                        // [N][E] bf16

    qkv_gemm<<<dim3(N_TOK / 128, 3 * E_DIM / 128), 256, 0, stream>>>(x, wqkv, bqkv, Qb, Kb, Vb);
    flash_attn<<<dim3(N_TOK / 64, NH), 256, 0, stream>>>(Qb, Kb, Vb, Ob);
    proj_gemm<<<dim3(N_TOK / 128, E_DIM / 128), 256, 0, stream>>>(Ob, wproj, bproj, out);
}

// Round 2
// 249.553 us; speedup vs baseline: 1.7556x; 1.7556x over previous
//
#include <hip/hip_runtime.h>

#define N_TOK 4096
#define E_DIM 1024
#define NH    16
#define HD    64

typedef __bf16 bf16x8 __attribute__((ext_vector_type(8)));
typedef __bf16 bf16x4 __attribute__((ext_vector_type(4)));
typedef float  f32x4  __attribute__((ext_vector_type(4)));

// ---------- 16-element loaders (global -> two bf16x8), with fp32->bf16 convert ----------
__device__ __forceinline__ void load16(const float* __restrict__ p, bf16x8& lo, bf16x8& hi) {
    float4 f0 = ((const float4*)p)[0];
    float4 f1 = ((const float4*)p)[1];
    float4 f2 = ((const float4*)p)[2];
    float4 f3 = ((const float4*)p)[3];
    lo = bf16x8{(__bf16)f0.x, (__bf16)f0.y, (__bf16)f0.z, (__bf16)f0.w,
                (__bf16)f1.x, (__bf16)f1.y, (__bf16)f1.z, (__bf16)f1.w};
    hi = bf16x8{(__bf16)f2.x, (__bf16)f2.y, (__bf16)f2.z, (__bf16)f2.w,
                (__bf16)f3.x, (__bf16)f3.y, (__bf16)f3.z, (__bf16)f3.w};
}
__device__ __forceinline__ void load16(const __bf16* __restrict__ p, bf16x8& lo, bf16x8& hi) {
    lo = *(const bf16x8*)p;
    hi = *(const bf16x8*)(p + 8);
}

// ---------- shared GEMM core: C[128x128] tile, out[n][f] = sum_k A[n][k]*B[f][k] ----------
#define LDSTR 40   // 32 + 8 pad (bf16 elems)

template <typename TA, typename TB>
__device__ __forceinline__ void gemm_core(const TA* __restrict__ A, const TB* __restrict__ B,
                                          const int K, const int rowBase, const int colBase,
                                          __bf16* As, __bf16* Bs, f32x4 (&acc)[4][4]) {
    const int tid  = threadIdx.x;
    const int lane = tid & 63;
    const int wid  = tid >> 6;
    const int wm = wid >> 1, wn = wid & 1;
    const int lr = lane & 15, lg = lane >> 4;
    const int srow = tid >> 1;            // 0..127
    const int shalf = (tid & 1) * 16;     // 0 or 16 (k offset)

    for (int kt = 0; kt < K; kt += 32) {
        bf16x8 alo, ahi, blo, bhi;
        load16(A + (size_t)(rowBase + srow) * K + kt + shalf, alo, ahi);
        load16(B + (size_t)(colBase + srow) * K + kt + shalf, blo, bhi);
        __syncthreads();   // readers of previous tile done
        *(bf16x8*)&As[srow * LDSTR + shalf]     = alo;
        *(bf16x8*)&As[srow * LDSTR + shalf + 8] = ahi;
        *(bf16x8*)&Bs[srow * LDSTR + shalf]     = blo;
        *(bf16x8*)&Bs[srow * LDSTR + shalf + 8] = bhi;
        __syncthreads();   // tile visible

        bf16x8 af[4], bfr[4];
#pragma unroll
        for (int i = 0; i < 4; ++i) {
            af[i]  = *(const bf16x8*)&As[(wm * 64 + i * 16 + lr) * LDSTR + lg * 8];
            bfr[i] = *(const bf16x8*)&Bs[(wn * 64 + i * 16 + lr) * LDSTR + lg * 8];
        }
#pragma unroll
        for (int i = 0; i < 4; ++i)
#pragma unroll
            for (int j = 0; j < 4; ++j)
                acc[i][j] = __builtin_amdgcn_mfma_f32_16x16x32_bf16(af[i], bfr[j], acc[i][j], 0, 0, 0);
    }
}

// ---------- kernel 1: QKV projection; Q,K row-major [h][n][d], V transposed [h][d][n] ----------
// Q pre-scaled by 1/sqrt(D) * log2(e) so attention can use exp2.
#define QSCALE 0.180336879f

__global__ __launch_bounds__(256) void qkv_gemm(const float* __restrict__ x,
                                                const float* __restrict__ wqkv,
                                                const float* __restrict__ bqkv,
                                                __bf16* __restrict__ Qb,
                                                __bf16* __restrict__ Kb,
                                                __bf16* __restrict__ VtG) {
    __shared__ __bf16 As[128 * LDSTR];
    __shared__ __bf16 Bs[128 * LDSTR];
    f32x4 acc[4][4];
#pragma unroll
    for (int i = 0; i < 4; ++i)
#pragma unroll
        for (int j = 0; j < 4; ++j)
            acc[i][j] = f32x4{0.f, 0.f, 0.f, 0.f};

    const int tm = blockIdx.x, tn = blockIdx.y;
    gemm_core(x, wqkv, E_DIM, tm * 128, tn * 128, As, Bs, acc);

    const int tid = threadIdx.x;
    const int lane = tid & 63, wid = tid >> 6;
    const int wm = wid >> 1, wn = wid & 1;
    const int lr = lane & 15, lg = lane >> 4;

#pragma unroll
    for (int ni = 0; ni < 4; ++ni) {
        const int f = tn * 128 + wn * 64 + ni * 16 + lr;   // 0..3071
        const float bias = bqkv[f];
        const int which = f >> 10;          // 0=Q 1=K 2=V (uniform per block)
        const int hh = (f & 1023) >> 6;
        const int dd = f & 63;
        if (which == 2) {
            __bf16* dst = VtG + ((size_t)hh * HD + dd) * N_TOK;
#pragma unroll
            for (int mi = 0; mi < 4; ++mi) {
                const int n0 = tm * 128 + wm * 64 + mi * 16 + lg * 4;
                bf16x4 v;
#pragma unroll
                for (int r = 0; r < 4; ++r) v[r] = (__bf16)(acc[mi][ni][r] + bias);
                *(bf16x4*)&dst[n0] = v;
            }
        } else {
            __bf16* dst = (which == 0) ? Qb : Kb;
            const float sc = (which == 0) ? QSCALE : 1.0f;
#pragma unroll
            for (int mi = 0; mi < 4; ++mi) {
#pragma unroll
                for (int r = 0; r < 4; ++r) {
                    const int n = tm * 128 + wm * 64 + mi * 16 + lg * 4 + r;
                    dst[((size_t)hh * N_TOK + n) * HD + dd] = (__bf16)((acc[mi][ni][r] + bias) * sc);
                }
            }
        }
    }
}

// ---------- kernel 2: flash attention (swapped operands, in-register softmax) ----------
// grid (64 qblocks, 16 heads), 256 threads = 4 waves, each wave owns 16 q-rows.
// S^T = mfma(K, Q): lane holds one q-col (lr) and kv = cb*16 + lg*4 + r.
#define KVB   64
#define FLSTR 72   // 64 + 8 pad (bf16 elems)

__global__ __launch_bounds__(256) void flash_attn(const __bf16* __restrict__ Qb,
                                                  const __bf16* __restrict__ Kb,
                                                  const __bf16* __restrict__ VtG,
                                                  __bf16* __restrict__ Ob) {
    __shared__ __bf16 Ks[KVB * FLSTR];
    __shared__ __bf16 Vs[HD * FLSTR];   // V^T: [d][kv]

    const int qblk = blockIdx.x, h = blockIdx.y;
    const int tid = threadIdx.x, lane = tid & 63, wid = tid >> 6;
    const int lr = lane & 15, lg = lane >> 4;

    const __bf16* Qh = Qb + (size_t)h * N_TOK * HD;
    const __bf16* Kh = Kb + (size_t)h * N_TOK * HD;
    const __bf16* Vh = VtG + (size_t)h * HD * N_TOK;

    // Q B-frag: col=q=lr, k(d) = kc*32 + lg*8 + j
    const int qrow = qblk * 64 + wid * 16 + lr;
    const bf16x8 qf0 = *(const bf16x8*)&Qh[(size_t)qrow * HD + lg * 8];
    const bf16x8 qf1 = *(const bf16x8*)&Qh[(size_t)qrow * HD + 32 + lg * 8];

    f32x4 o[4];   // O^T frags: row=d=db*16+lg*4+r, col=q=lr
#pragma unroll
    for (int i = 0; i < 4; ++i) o[i] = f32x4{0.f, 0.f, 0.f, 0.f};
    float m = -INFINITY, l = 0.f;

    const int srow = tid >> 2, sseg = (tid & 3) * 16;   // staging: 4 threads/row, 16 elems each

    for (int kv0 = 0; kv0 < N_TOK; kv0 += KVB) {
        bf16x8 klo, khi, vlo, vhi;
        load16(&Kh[(size_t)(kv0 + srow) * HD + sseg], klo, khi);
        load16(&Vh[(size_t)srow * N_TOK + kv0 + sseg], vlo, vhi);
        __syncthreads();   // previous tile's readers done
        *(bf16x8*)&Ks[srow * FLSTR + sseg]     = klo;
        *(bf16x8*)&Ks[srow * FLSTR + sseg + 8] = khi;
        *(bf16x8*)&Vs[srow * FLSTR + sseg]     = vlo;
        *(bf16x8*)&Vs[srow * FLSTR + sseg + 8] = vhi;
        __syncthreads();

        // S^T = K Q^T   (A=K-frag: row=kv, k=d)
        f32x4 st[4];
#pragma unroll
        for (int cb = 0; cb < 4; ++cb) {
            f32x4 a = f32x4{0.f, 0.f, 0.f, 0.f};
            const bf16x8 kf0 = *(const bf16x8*)&Ks[(cb * 16 + lr) * FLSTR + lg * 8];
            a = __builtin_amdgcn_mfma_f32_16x16x32_bf16(kf0, qf0, a, 0, 0, 0);
            const bf16x8 kf1 = *(const bf16x8*)&Ks[(cb * 16 + lr) * FLSTR + 32 + lg * 8];
            a = __builtin_amdgcn_mfma_f32_16x16x32_bf16(kf1, qf1, a, 0, 0, 0);
            st[cb] = a;
        }

        // online softmax — all values for this lane's q live in-register (16 of 64 kv),
        // full-row reduce needs only xor-16 and xor-32 (lanes sharing lr).
        float mx = fmaxf(fmaxf(fmaxf(st[0][0], st[0][1]), fmaxf(st[0][2], st[0][3])),
                         fmaxf(fmaxf(st[1][0], st[1][1]), fmaxf(st[1][2], st[1][3])));
        mx = fmaxf(mx, fmaxf(fmaxf(fmaxf(st[2][0], st[2][1]), fmaxf(st[2][2], st[2][3])),
                             fmaxf(fmaxf(st[3][0], st[3][1]), fmaxf(st[3][2], st[3][3]))));
        mx = fmaxf(mx, __shfl_xor(mx, 16));
        mx = fmaxf(mx, __shfl_xor(mx, 32));
        const float mn = fmaxf(m, mx);
        const float alpha = exp2f(m - mn);
        float p[4][4];
        float ps = 0.f;
#pragma unroll
        for (int cb = 0; cb < 4; ++cb)
#pragma unroll
            for (int r = 0; r < 4; ++r) { p[cb][r] = exp2f(st[cb][r] - mn); ps += p[cb][r]; }
        ps += __shfl_xor(ps, 16);
        ps += __shfl_xor(ps, 32);
        l = l * alpha + ps;
        m = mn;
#pragma unroll
        for (int db = 0; db < 4; ++db)
#pragma unroll
            for (int r = 0; r < 4; ++r) o[db][r] *= alpha;

        // P^T B-frags, purely in-register: slot j of mfma kc -> kv = 32kc + (j>>2)*16 + lg*4 + (j&3)
        const bf16x8 pf0 = bf16x8{(__bf16)p[0][0], (__bf16)p[0][1], (__bf16)p[0][2], (__bf16)p[0][3],
                                  (__bf16)p[1][0], (__bf16)p[1][1], (__bf16)p[1][2], (__bf16)p[1][3]};
        const bf16x8 pf1 = bf16x8{(__bf16)p[2][0], (__bf16)p[2][1], (__bf16)p[2][2], (__bf16)p[2][3],
                                  (__bf16)p[3][0], (__bf16)p[3][1], (__bf16)p[3][2], (__bf16)p[3][3]};

        // O^T += V^T P^T  (A=V^T-frag: row=d, same permuted kv-slot mapping as P)
#pragma unroll
        for (int db = 0; db < 4; ++db) {
            const int vrow = (db * 16 + lr) * FLSTR;
            const bf16x4 a0 = *(const bf16x4*)&Vs[vrow + lg * 4];
            const bf16x4 a1 = *(const bf16x4*)&Vs[vrow + 16 + lg * 4];
            const bf16x4 a2 = *(const bf16x4*)&Vs[vrow + 32 + lg * 4];
            const bf16x4 a3 = *(const bf16x4*)&Vs[vrow + 48 + lg * 4];
            const bf16x8 vf0 = bf16x8{a0[0], a0[1], a0[2], a0[3], a1[0], a1[1], a1[2], a1[3]};
            const bf16x8 vf1 = bf16x8{a2[0], a2[1], a2[2], a2[3], a3[0], a3[1], a3[2], a3[3]};
            o[db] = __builtin_amdgcn_mfma_f32_16x16x32_bf16(vf0, pf0, o[db], 0, 0, 0);
            o[db] = __builtin_amdgcn_mfma_f32_16x16x32_bf16(vf1, pf1, o[db], 0, 0, 0);
        }
    }

    // epilogue: normalize, store bf16 [N][E] with vector stores (d contiguous per lane)
    const float inv = 1.0f / l;
    const int n = qblk * 64 + wid * 16 + lr;
#pragma unroll
    for (int db = 0; db < 4; ++db) {
        bf16x4 v;
#pragma unroll
        for (int r = 0; r < 4; ++r) v[r] = (__bf16)(o[db][r] * inv);
        *(bf16x4*)&Ob[(size_t)n * E_DIM + h * HD + db * 16 + lg * 4] = v;
    }
}

// ---------- kernel 3: output projection ----------
__global__ __launch_bounds__(256) void proj_gemm(const __bf16* __restrict__ Ob,
                                                 const float* __restrict__ wp,
                                                 const float* __restrict__ bp,
                                                 float* __restrict__ out) {
    __shared__ __bf16 As[128 * LDSTR];
    __shared__ __bf16 Bs[128 * LDSTR];
    f32x4 acc[4][4];
#pragma unroll
    for (int i = 0; i < 4; ++i)
#pragma unroll
        for (int j = 0; j < 4; ++j)
            acc[i][j] = f32x4{0.f, 0.f, 0.f, 0.f};

    const int tm = blockIdx.x, tn = blockIdx.y;
    gemm_core(Ob, wp, E_DIM, tm * 128, tn * 128, As, Bs, acc);

    const int tid = threadIdx.x;
    const int lane = tid & 63, wid = tid >> 6;
    const int wm = wid >> 1, wn = wid & 1;
    const int lr = lane & 15, lg = lane >> 4;

#pragma unroll
    for (int ni = 0; ni < 4; ++ni) {
        const int f = tn * 128 + wn * 64 + ni * 16 + lr;
        const float bias = bp[f];
#pragma unroll
        for (int mi = 0; mi < 4; ++mi) {
#pragma unroll
            for (int r = 0; r < 4; ++r) {
                const int n = tm * 128 + wm * 64 + mi * 16 + lg * 4 + r;
                out[(size_t)n * E_DIM + f] = acc[mi][ni][r] + bias;
            }
        }
    }
}

// ---------- launch ----------
extern "C" void kernel_launch(void* const* d_in, const int* in_sizes, int n_in,
                              void* d_out, int out_size, void* d_ws, size_t ws_size,
                              hipStream_t stream) {
    const float* x     = (const float*)d_in[0];
    const float* wqkv  = (const float*)d_in[1];
    const float* bqkv  = (const float*)d_in[2];
    const float* wproj = (const float*)d_in[3];
    const float* bproj = (const float*)d_in[4];
    float* out = (float*)d_out;

    const size_t headElems = (size_t)NH * N_TOK * HD;   // 4M elems
    __bf16* Qb  = (__bf16*)d_ws;
    __bf16* Kb  = Qb + headElems;
    __bf16* VtG = Kb + headElems;                       // [H][D][N]
    __bf16* Ob  = VtG + headElems;                      // [N][E] bf16

    qkv_gemm<<<dim3(N_TOK / 128, 3 * E_DIM / 128), 256, 0, stream>>>(x, wqkv, bqkv, Qb, Kb, VtG);
    flash_attn<<<dim3(N_TOK / 64, NH), 256, 0, stream>>>(Qb, Kb, VtG, Ob);
    proj_gemm<<<dim3(N_TOK / 128, E_DIM / 128), 256, 0, stream>>>(Ob, wproj, bproj, out);
}

// Round 3
// 223.921 us; speedup vs baseline: 1.9565x; 1.1145x over previous
//
#include <hip/hip_runtime.h>

#define N_TOK 4096
#define E_DIM 1024
#define NH    16
#define HD    64

typedef __bf16 bf16x8 __attribute__((ext_vector_type(8)));
typedef __bf16 bf16x4 __attribute__((ext_vector_type(4)));
typedef float  f32x4  __attribute__((ext_vector_type(4)));

// ---------- 16-element loaders (global -> two bf16x8), with fp32->bf16 convert ----------
__device__ __forceinline__ void load16(const float* __restrict__ p, bf16x8& lo, bf16x8& hi) {
    float4 f0 = ((const float4*)p)[0];
    float4 f1 = ((const float4*)p)[1];
    float4 f2 = ((const float4*)p)[2];
    float4 f3 = ((const float4*)p)[3];
    lo = bf16x8{(__bf16)f0.x, (__bf16)f0.y, (__bf16)f0.z, (__bf16)f0.w,
                (__bf16)f1.x, (__bf16)f1.y, (__bf16)f1.z, (__bf16)f1.w};
    hi = bf16x8{(__bf16)f2.x, (__bf16)f2.y, (__bf16)f2.z, (__bf16)f2.w,
                (__bf16)f3.x, (__bf16)f3.y, (__bf16)f3.z, (__bf16)f3.w};
}
__device__ __forceinline__ void load16(const __bf16* __restrict__ p, bf16x8& lo, bf16x8& hi) {
    lo = *(const bf16x8*)p;
    hi = *(const bf16x8*)(p + 8);
}

// ---------- shared GEMM core: C[128x128] tile, out[n][f] = sum_k A[n][k]*B[f][k] ----------
#define LDSTR 40   // 32 + 8 pad (bf16 elems)

template <typename TA, typename TB>
__device__ __forceinline__ void gemm_core(const TA* __restrict__ A, const TB* __restrict__ B,
                                          const int K, const int rowBase, const int colBase,
                                          __bf16* As, __bf16* Bs, f32x4 (&acc)[4][4]) {
    const int tid  = threadIdx.x;
    const int lane = tid & 63;
    const int wid  = tid >> 6;
    const int wm = wid >> 1, wn = wid & 1;
    const int lr = lane & 15, lg = lane >> 4;
    const int srow = tid >> 1;            // 0..127
    const int shalf = (tid & 1) * 16;     // 0 or 16 (k offset)

    for (int kt = 0; kt < K; kt += 32) {
        bf16x8 alo, ahi, blo, bhi;
        load16(A + (size_t)(rowBase + srow) * K + kt + shalf, alo, ahi);
        load16(B + (size_t)(colBase + srow) * K + kt + shalf, blo, bhi);
        __syncthreads();   // readers of previous tile done
        *(bf16x8*)&As[srow * LDSTR + shalf]     = alo;
        *(bf16x8*)&As[srow * LDSTR + shalf + 8] = ahi;
        *(bf16x8*)&Bs[srow * LDSTR + shalf]     = blo;
        *(bf16x8*)&Bs[srow * LDSTR + shalf + 8] = bhi;
        __syncthreads();   // tile visible

        bf16x8 af[4], bfr[4];
#pragma unroll
        for (int i = 0; i < 4; ++i) {
            af[i]  = *(const bf16x8*)&As[(wm * 64 + i * 16 + lr) * LDSTR + lg * 8];
            bfr[i] = *(const bf16x8*)&Bs[(wn * 64 + i * 16 + lr) * LDSTR + lg * 8];
        }
#pragma unroll
        for (int i = 0; i < 4; ++i)
#pragma unroll
            for (int j = 0; j < 4; ++j)
                acc[i][j] = __builtin_amdgcn_mfma_f32_16x16x32_bf16(af[i], bfr[j], acc[i][j], 0, 0, 0);
    }
}

// ---------- kernel 1: QKV projection; Q,K row-major [h][n][d], V transposed+permuted [h][d][n'] ----------
// Q pre-scaled by 1/sqrt(D) * log2(e) so attention can use exp2.
// V column perm within each 64-token block: kv = hi*32+mid*16+g*4+r -> pos = hi*32+g*8+mid*4+r,
// so the flash PV A-fragment is one contiguous bf16x8 at pos = kc*32 + lg*8.
#define QSCALE 0.180336879f

__global__ __launch_bounds__(256) void qkv_gemm(const float* __restrict__ x,
                                                const float* __restrict__ wqkv,
                                                const float* __restrict__ bqkv,
                                                __bf16* __restrict__ Qb,
                                                __bf16* __restrict__ Kb,
                                                __bf16* __restrict__ VtG) {
    __shared__ __bf16 As[128 * LDSTR];
    __shared__ __bf16 Bs[128 * LDSTR];
    f32x4 acc[4][4];
#pragma unroll
    for (int i = 0; i < 4; ++i)
#pragma unroll
        for (int j = 0; j < 4; ++j)
            acc[i][j] = f32x4{0.f, 0.f, 0.f, 0.f};

    const int tm = blockIdx.x, tn = blockIdx.y;
    gemm_core(x, wqkv, E_DIM, tm * 128, tn * 128, As, Bs, acc);

    const int tid = threadIdx.x;
    const int lane = tid & 63, wid = tid >> 6;
    const int wm = wid >> 1, wn = wid & 1;
    const int lr = lane & 15, lg = lane >> 4;

#pragma unroll
    for (int ni = 0; ni < 4; ++ni) {
        const int f = tn * 128 + wn * 64 + ni * 16 + lr;   // 0..3071
        const float bias = bqkv[f];
        const int which = f >> 10;          // 0=Q 1=K 2=V (uniform per block)
        const int hh = (f & 1023) >> 6;
        const int dd = f & 63;
        if (which == 2) {
            __bf16* dst = VtG + ((size_t)hh * HD + dd) * N_TOK;
#pragma unroll
            for (int mi = 0; mi < 4; ++mi) {
                const int n0 = tm * 128 + wm * 64 + mi * 16 + lg * 4;
                const int nl = n0 & 63;
                const int pos = (n0 & ~63) + ((nl >> 5) << 5) + (((nl >> 2) & 3) << 3) + (((nl >> 4) & 1) << 2);
                bf16x4 v;
#pragma unroll
                for (int r = 0; r < 4; ++r) v[r] = (__bf16)(acc[mi][ni][r] + bias);
                *(bf16x4*)&dst[pos] = v;
            }
        } else {
            __bf16* dst = (which == 0) ? Qb : Kb;
            const float sc = (which == 0) ? QSCALE : 1.0f;
#pragma unroll
            for (int mi = 0; mi < 4; ++mi) {
#pragma unroll
                for (int r = 0; r < 4; ++r) {
                    const int n = tm * 128 + wm * 64 + mi * 16 + lg * 4 + r;
                    dst[((size_t)hh * N_TOK + n) * HD + dd] = (__bf16)((acc[mi][ni][r] + bias) * sc);
                }
            }
        }
    }
}

// ---------- kernel 2: flash attention ----------
// grid (32 qblocks, 16 heads), 256 threads = 4 waves; each wave owns 32 q-rows (2 groups of 16).
// S^T = mfma(K, Q): lane holds q-col (lr) and kv = cb*16 + lg*4 + r, in-register softmax,
// l via ones-MFMA, defer-max rescale, register prefetch of next K/V tile.
#define QBLK  128
#define KVB   64
#define FLSTR 72   // 64 + 8 pad (bf16 elems)

__global__ __launch_bounds__(256) void flash_attn(const __bf16* __restrict__ Qb,
                                                  const __bf16* __restrict__ Kb,
                                                  const __bf16* __restrict__ Vp,
                                                  __bf16* __restrict__ Ob) {
    __shared__ __bf16 Ks[KVB * FLSTR];
    __shared__ __bf16 Vs[HD * FLSTR];   // V^T, permuted cols: [d][pos]

    const int qblk = blockIdx.x, h = blockIdx.y;
    const int tid = threadIdx.x, lane = tid & 63, wid = tid >> 6;
    const int lr = lane & 15, lg = lane >> 4;

    const __bf16* Qh = Qb + (size_t)h * N_TOK * HD;
    const __bf16* Kh = Kb + (size_t)h * N_TOK * HD;
    const __bf16* Vh = Vp + (size_t)h * HD * N_TOK;

    // Q B-frags: col=q=lr, k(d) = kc*32 + lg*8 + j ; two q-groups per wave
    bf16x8 qf[2][2];
#pragma unroll
    for (int g = 0; g < 2; ++g) {
        const size_t row = (size_t)qblk * QBLK + wid * 32 + g * 16 + lr;
        qf[g][0] = *(const bf16x8*)&Qh[row * HD + lg * 8];
        qf[g][1] = *(const bf16x8*)&Qh[row * HD + 32 + lg * 8];
    }

    f32x4 o[2][4];    // O^T frags: row=d=db*16+lg*4+r, col=q=lr
    f32x4 ol[2];      // running row-sum (l) accumulator; only reg 0 is read
#pragma unroll
    for (int g = 0; g < 2; ++g) {
        ol[g] = f32x4{0.f, 0.f, 0.f, 0.f};
#pragma unroll
        for (int i = 0; i < 4; ++i) o[g][i] = f32x4{0.f, 0.f, 0.f, 0.f};
    }
    float m[2] = {-INFINITY, -INFINITY};

    const bf16x8 ones = bf16x8{(__bf16)1.f, (__bf16)1.f, (__bf16)1.f, (__bf16)1.f,
                               (__bf16)1.f, (__bf16)1.f, (__bf16)1.f, (__bf16)1.f};

    const int srow = tid >> 2, sseg = (tid & 3) * 16;   // staging: 4 threads/row, 16 elems each
    const __bf16* kStage = &Kh[(size_t)srow * HD + sseg];
    const __bf16* vStage = &Vh[(size_t)srow * N_TOK + sseg];

    bf16x8 kr0, kr1, vr0, vr1;
    load16(kStage, kr0, kr1);
    load16(vStage, vr0, vr1);

    for (int kv0 = 0; kv0 < N_TOK; kv0 += KVB) {
        __syncthreads();   // previous tile's readers done
        *(bf16x8*)&Ks[srow * FLSTR + sseg]     = kr0;
        *(bf16x8*)&Ks[srow * FLSTR + sseg + 8] = kr1;
        *(bf16x8*)&Vs[srow * FLSTR + sseg]     = vr0;
        *(bf16x8*)&Vs[srow * FLSTR + sseg + 8] = vr1;
        __syncthreads();

        // prefetch next tile into registers (latency hides under compute below)
        if (kv0 + KVB < N_TOK) {
            load16(kStage + (size_t)(kv0 + KVB) * HD, kr0, kr1);
            load16(vStage + (kv0 + KVB), vr0, vr1);
        }

        // S^T = K Q^T   (A=K-frag: row=kv, k=d) — K frags shared by both q-groups
        f32x4 st[2][4];
#pragma unroll
        for (int cb = 0; cb < 4; ++cb) {
            const bf16x8 kf0 = *(const bf16x8*)&Ks[(cb * 16 + lr) * FLSTR + lg * 8];
            const bf16x8 kf1 = *(const bf16x8*)&Ks[(cb * 16 + lr) * FLSTR + 32 + lg * 8];
#pragma unroll
            for (int g = 0; g < 2; ++g) {
                f32x4 a = f32x4{0.f, 0.f, 0.f, 0.f};
                a = __builtin_amdgcn_mfma_f32_16x16x32_bf16(kf0, qf[g][0], a, 0, 0, 0);
                a = __builtin_amdgcn_mfma_f32_16x16x32_bf16(kf1, qf[g][1], a, 0, 0, 0);
                st[g][cb] = a;
            }
        }

        // per-q-column max (lanes sharing lr hold the other kv's: xor16, xor32)
        float mx[2];
#pragma unroll
        for (int g = 0; g < 2; ++g) {
            float a0 = fmaxf(fmaxf(st[g][0][0], st[g][0][1]), fmaxf(st[g][0][2], st[g][0][3]));
            float a1 = fmaxf(fmaxf(st[g][1][0], st[g][1][1]), fmaxf(st[g][1][2], st[g][1][3]));
            float a2 = fmaxf(fmaxf(st[g][2][0], st[g][2][1]), fmaxf(st[g][2][2], st[g][2][3]));
            float a3 = fmaxf(fmaxf(st[g][3][0], st[g][3][1]), fmaxf(st[g][3][2], st[g][3][3]));
            float a = fmaxf(fmaxf(a0, a1), fmaxf(a2, a3));
            a = fmaxf(a, __shfl_xor(a, 16));
            a = fmaxf(a, __shfl_xor(a, 32));
            mx[g] = a;
        }

        // defer-max: skip O/l rescale while per-tile growth <= 2^8 (exp2 domain)
        if (!__all(mx[0] <= m[0] + 8.f && mx[1] <= m[1] + 8.f)) {
#pragma unroll
            for (int g = 0; g < 2; ++g) {
                const float mn = fmaxf(m[g], mx[g]);
                const float alpha = exp2f(m[g] - mn);
                m[g] = mn;
#pragma unroll
                for (int db = 0; db < 4; ++db)
#pragma unroll
                    for (int r = 0; r < 4; ++r) o[g][db][r] *= alpha;
                ol[g][0] *= alpha;
            }
        }

        // P = exp2(S^T - m), packed straight into PV B-frags; l += colsum(P) via ones-MFMA
        bf16x8 pf[2][2];
#pragma unroll
        for (int g = 0; g < 2; ++g) {
            float pv[16];
#pragma unroll
            for (int cb = 0; cb < 4; ++cb)
#pragma unroll
                for (int r = 0; r < 4; ++r) pv[cb * 4 + r] = exp2f(st[g][cb][r] - m[g]);
            pf[g][0] = bf16x8{(__bf16)pv[0],  (__bf16)pv[1],  (__bf16)pv[2],  (__bf16)pv[3],
                              (__bf16)pv[4],  (__bf16)pv[5],  (__bf16)pv[6],  (__bf16)pv[7]};
            pf[g][1] = bf16x8{(__bf16)pv[8],  (__bf16)pv[9],  (__bf16)pv[10], (__bf16)pv[11],
                              (__bf16)pv[12], (__bf16)pv[13], (__bf16)pv[14], (__bf16)pv[15]};
            ol[g] = __builtin_amdgcn_mfma_f32_16x16x32_bf16(ones, pf[g][0], ol[g], 0, 0, 0);
            ol[g] = __builtin_amdgcn_mfma_f32_16x16x32_bf16(ones, pf[g][1], ol[g], 0, 0, 0);
        }

        // O^T += V^T P^T ; V frags contiguous b128 thanks to the global perm, shared by q-groups
#pragma unroll
        for (int db = 0; db < 4; ++db) {
            const int vrow = (db * 16 + lr) * FLSTR;
            const bf16x8 vf0 = *(const bf16x8*)&Vs[vrow + lg * 8];
            const bf16x8 vf1 = *(const bf16x8*)&Vs[vrow + 32 + lg * 8];
#pragma unroll
            for (int g = 0; g < 2; ++g) {
                o[g][db] = __builtin_amdgcn_mfma_f32_16x16x32_bf16(vf0, pf[g][0], o[g][db], 0, 0, 0);
                o[g][db] = __builtin_amdgcn_mfma_f32_16x16x32_bf16(vf1, pf[g][1], o[g][db], 0, 0, 0);
            }
        }
    }

    // epilogue: normalize, store bf16 [N][E] with vector stores (d contiguous per lane)
#pragma unroll
    for (int g = 0; g < 2; ++g) {
        const float inv = 1.0f / ol[g][0];
        const size_t n = (size_t)qblk * QBLK + wid * 32 + g * 16 + lr;
#pragma unroll
        for (int db = 0; db < 4; ++db) {
            bf16x4 v;
#pragma unroll
            for (int r = 0; r < 4; ++r) v[r] = (__bf16)(o[g][db][r] * inv);
            *(bf16x4*)&Ob[n * E_DIM + h * HD + db * 16 + lg * 4] = v;
        }
    }
}

// ---------- kernel 3: output projection ----------
__global__ __launch_bounds__(256) void proj_gemm(const __bf16* __restrict__ Ob,
                                                 const float* __restrict__ wp,
                                                 const float* __restrict__ bp,
                                                 float* __restrict__ out) {
    __shared__ __bf16 As[128 * LDSTR];
    __shared__ __bf16 Bs[128 * LDSTR];
    f32x4 acc[4][4];
#pragma unroll
    for (int i = 0; i < 4; ++i)
#pragma unroll
        for (int j = 0; j < 4; ++j)
            acc[i][j] = f32x4{0.f, 0.f, 0.f, 0.f};

    const int tm = blockIdx.x, tn = blockIdx.y;
    gemm_core(Ob, wp, E_DIM, tm * 128, tn * 128, As, Bs, acc);

    const int tid = threadIdx.x;
    const int lane = tid & 63, wid = tid >> 6;
    const int wm = wid >> 1, wn = wid & 1;
    const int lr = lane & 15, lg = lane >> 4;

#pragma unroll
    for (int ni = 0; ni < 4; ++ni) {
        const int f = tn * 128 + wn * 64 + ni * 16 + lr;
        const float bias = bp[f];
#pragma unroll
        for (int mi = 0; mi < 4; ++mi) {
#pragma unroll
            for (int r = 0; r < 4; ++r) {
                const int n = tm * 128 + wm * 64 + mi * 16 + lg * 4 + r;
                out[(size_t)n * E_DIM + f] = acc[mi][ni][r] + bias;
            }
        }
    }
}

// ---------- launch ----------
extern "C" void kernel_launch(void* const* d_in, const int* in_sizes, int n_in,
                              void* d_out, int out_size, void* d_ws, size_t ws_size,
                              hipStream_t stream) {
    const float* x     = (const float*)d_in[0];
    const float* wqkv  = (const float*)d_in[1];
    const float* bqkv  = (const float*)d_in[2];
    const float* wproj = (const float*)d_in[3];
    const float* bproj = (const float*)d_in[4];
    float* out = (float*)d_out;

    const size_t headElems = (size_t)NH * N_TOK * HD;   // 4M elems
    __bf16* Qb  = (__bf16*)d_ws;
    __bf16* Kb  = Qb + headElems;
    __bf16* VtG = Kb + headElems;                       // [H][D][N'] (permuted cols)
    __bf16* Ob  = VtG + headElems;                      // [N][E] bf16

    qkv_gemm<<<dim3(N_TOK / 128, 3 * E_DIM / 128), 256, 0, stream>>>(x, wqkv, bqkv, Qb, Kb, VtG);
    flash_attn<<<dim3(N_TOK / QBLK, NH), 256, 0, stream>>>(Qb, Kb, VtG, Ob);
    proj_gemm<<<dim3(N_TOK / 128, E_DIM / 128), 256, 0, stream>>>(Ob, wproj, bproj, out);
}

// Round 4
// 212.221 us; speedup vs baseline: 2.0644x; 1.0551x over previous
//
#include <hip/hip_runtime.h>

#define N_TOK 4096
#define E_DIM 1024
#define NH    16
#define HD    64

typedef __bf16 bf16x8 __attribute__((ext_vector_type(8)));
typedef __bf16 bf16x4 __attribute__((ext_vector_type(4)));
typedef float  f32x4  __attribute__((ext_vector_type(4)));
typedef float  f32x16 __attribute__((ext_vector_type(16)));

__device__ __forceinline__ f32x16 zero16() {
    f32x16 z;
#pragma unroll
    for (int i = 0; i < 16; ++i) z[i] = 0.f;
    return z;
}

// pack two floats into one u32 of 2 bf16
__device__ __forceinline__ unsigned pk2(float a, float b) {
    union { __bf16 h[2]; unsigned u; } t;
    t.h[0] = (__bf16)a; t.h[1] = (__bf16)b;
    return t.u;
}

// ---------- 16-element loaders (global -> two bf16x8), with fp32->bf16 convert ----------
__device__ __forceinline__ void load16(const float* __restrict__ p, bf16x8& lo, bf16x8& hi) {
    float4 f0 = ((const float4*)p)[0];
    float4 f1 = ((const float4*)p)[1];
    float4 f2 = ((const float4*)p)[2];
    float4 f3 = ((const float4*)p)[3];
    lo = bf16x8{(__bf16)f0.x, (__bf16)f0.y, (__bf16)f0.z, (__bf16)f0.w,
                (__bf16)f1.x, (__bf16)f1.y, (__bf16)f1.z, (__bf16)f1.w};
    hi = bf16x8{(__bf16)f2.x, (__bf16)f2.y, (__bf16)f2.z, (__bf16)f2.w,
                (__bf16)f3.x, (__bf16)f3.y, (__bf16)f3.z, (__bf16)f3.w};
}
__device__ __forceinline__ void load16(const __bf16* __restrict__ p, bf16x8& lo, bf16x8& hi) {
    lo = *(const bf16x8*)p;
    hi = *(const bf16x8*)(p + 8);
}

// ---------- shared GEMM core: C[128x128] tile, out[n][f] = sum_k A[n][k]*B[f][k] ----------
#define LDSTR 40   // 32 + 8 pad (bf16 elems)

template <typename TA, typename TB>
__device__ __forceinline__ void gemm_core(const TA* __restrict__ A, const TB* __restrict__ B,
                                          const int K, const int rowBase, const int colBase,
                                          __bf16* As, __bf16* Bs, f32x4 (&acc)[4][4]) {
    const int tid  = threadIdx.x;
    const int lane = tid & 63;
    const int wid  = tid >> 6;
    const int wm = wid >> 1, wn = wid & 1;
    const int lr = lane & 15, lg = lane >> 4;
    const int srow = tid >> 1;            // 0..127
    const int shalf = (tid & 1) * 16;     // 0 or 16 (k offset)

    for (int kt = 0; kt < K; kt += 32) {
        bf16x8 alo, ahi, blo, bhi;
        load16(A + (size_t)(rowBase + srow) * K + kt + shalf, alo, ahi);
        load16(B + (size_t)(colBase + srow) * K + kt + shalf, blo, bhi);
        __syncthreads();   // readers of previous tile done
        *(bf16x8*)&As[srow * LDSTR + shalf]     = alo;
        *(bf16x8*)&As[srow * LDSTR + shalf + 8] = ahi;
        *(bf16x8*)&Bs[srow * LDSTR + shalf]     = blo;
        *(bf16x8*)&Bs[srow * LDSTR + shalf + 8] = bhi;
        __syncthreads();   // tile visible

        bf16x8 af[4], bfr[4];
#pragma unroll
        for (int i = 0; i < 4; ++i) {
            af[i]  = *(const bf16x8*)&As[(wm * 64 + i * 16 + lr) * LDSTR + lg * 8];
            bfr[i] = *(const bf16x8*)&Bs[(wn * 64 + i * 16 + lr) * LDSTR + lg * 8];
        }
#pragma unroll
        for (int i = 0; i < 4; ++i)
#pragma unroll
            for (int j = 0; j < 4; ++j)
                acc[i][j] = __builtin_amdgcn_mfma_f32_16x16x32_bf16(af[i], bfr[j], acc[i][j], 0, 0, 0);
    }
}

// ---------- kernel 1: QKV projection; Q,K row-major [h][n][d], V transposed [h][d][n] ----------
// Q pre-scaled by 1/sqrt(D) * log2(e) so attention can use exp2.
#define QSCALE 0.180336879f

__global__ __launch_bounds__(256) void qkv_gemm(const float* __restrict__ x,
                                                const float* __restrict__ wqkv,
                                                const float* __restrict__ bqkv,
                                                __bf16* __restrict__ Qb,
                                                __bf16* __restrict__ Kb,
                                                __bf16* __restrict__ VtG) {
    __shared__ __bf16 As[128 * LDSTR];
    __shared__ __bf16 Bs[128 * LDSTR];
    f32x4 acc[4][4];
#pragma unroll
    for (int i = 0; i < 4; ++i)
#pragma unroll
        for (int j = 0; j < 4; ++j)
            acc[i][j] = f32x4{0.f, 0.f, 0.f, 0.f};

    const int tm = blockIdx.x, tn = blockIdx.y;
    gemm_core(x, wqkv, E_DIM, tm * 128, tn * 128, As, Bs, acc);

    const int tid = threadIdx.x;
    const int lane = tid & 63, wid = tid >> 6;
    const int wm = wid >> 1, wn = wid & 1;
    const int lr = lane & 15, lg = lane >> 4;

#pragma unroll
    for (int ni = 0; ni < 4; ++ni) {
        const int f = tn * 128 + wn * 64 + ni * 16 + lr;   // 0..3071
        const float bias = bqkv[f];
        const int which = f >> 10;          // 0=Q 1=K 2=V (uniform per block)
        const int hh = (f & 1023) >> 6;
        const int dd = f & 63;
        if (which == 2) {
            __bf16* dst = VtG + ((size_t)hh * HD + dd) * N_TOK;
#pragma unroll
            for (int mi = 0; mi < 4; ++mi) {
                const int n0 = tm * 128 + wm * 64 + mi * 16 + lg * 4;
                bf16x4 v;
#pragma unroll
                for (int r = 0; r < 4; ++r) v[r] = (__bf16)(acc[mi][ni][r] + bias);
                *(bf16x4*)&dst[n0] = v;
            }
        } else {
            __bf16* dst = (which == 0) ? Qb : Kb;
            const float sc = (which == 0) ? QSCALE : 1.0f;
#pragma unroll
            for (int mi = 0; mi < 4; ++mi) {
#pragma unroll
                for (int r = 0; r < 4; ++r) {
                    const int n = tm * 128 + wm * 64 + mi * 16 + lg * 4 + r;
                    dst[((size_t)hh * N_TOK + n) * HD + dd] = (__bf16)((acc[mi][ni][r] + bias) * sc);
                }
            }
        }
    }
}

// ---------- kernel 2: flash attention, 32x32x16 MFMA ----------
// grid (32 qblocks, 16 heads), 256 threads = 4 waves; each wave owns 32 q-rows.
// S^T = mfma32(K, Q): lane (q=lane&31, hi=lane>>5) holds S rows r with bit2(r)==hi.
// P B-frag for PV needs rows 16s+8hi+j -> exchange 2 u32/window via shfl_xor(32).
#define QBLK  128
#define KVB   64
#define KST   72   // 64 + 8 pad

__global__ __launch_bounds__(256) void flash_attn(const __bf16* __restrict__ Qb,
                                                  const __bf16* __restrict__ Kb,
                                                  const __bf16* __restrict__ Vt,
                                                  __bf16* __restrict__ Ob) {
    __shared__ __bf16 Ks[KVB * KST];   // [kv][d]
    __shared__ __bf16 Vs[HD * KST];    // [d][kv]

    const int qblk = blockIdx.x, h = blockIdx.y;
    const int tid = threadIdx.x, lane = tid & 63, wid = tid >> 6;
    const int lq = lane & 31, hi = lane >> 5;

    const __bf16* Qh = Qb + (size_t)h * N_TOK * HD;
    const __bf16* Kh = Kb + (size_t)h * N_TOK * HD;
    const __bf16* Vh = Vt + (size_t)h * HD * N_TOK;

    // Q B-frags: col=q=lq, k-slot (hi,j): d = sd*16 + hi*8 + j
    const size_t qrow = (size_t)qblk * QBLK + wid * 32 + lq;
    bf16x8 qf[4];
#pragma unroll
    for (int sd = 0; sd < 4; ++sd)
        qf[sd] = *(const bf16x8*)&Qh[qrow * HD + sd * 16 + hi * 8];

    f32x16 o0 = zero16(), o1 = zero16(), lacc = zero16();
    float m = -INFINITY;

    const bf16x8 ones = bf16x8{(__bf16)1.f, (__bf16)1.f, (__bf16)1.f, (__bf16)1.f,
                               (__bf16)1.f, (__bf16)1.f, (__bf16)1.f, (__bf16)1.f};

    const int srow = tid >> 2, sseg = (tid & 3) * 16;   // 64 rows x 64 cols staging
    const __bf16* kStage = &Kh[(size_t)srow * HD + sseg];
    const __bf16* vStage = &Vh[(size_t)srow * N_TOK + sseg];

    bf16x8 kr0, kr1, vr0, vr1;
    load16(kStage, kr0, kr1);
    load16(vStage, vr0, vr1);

    for (int kv0 = 0; kv0 < N_TOK; kv0 += KVB) {
        __syncthreads();   // previous tile's readers done
        *(bf16x8*)&Ks[srow * KST + sseg]     = kr0;
        *(bf16x8*)&Ks[srow * KST + sseg + 8] = kr1;
        *(bf16x8*)&Vs[srow * KST + sseg]     = vr0;
        *(bf16x8*)&Vs[srow * KST + sseg + 8] = vr1;
        __syncthreads();

        if (kv0 + KVB < N_TOK) {   // register prefetch of next tile
            load16(kStage + (size_t)(kv0 + KVB) * HD, kr0, kr1);
            load16(vStage + (kv0 + KVB), vr0, vr1);
        }

        // S^T = K Q^T : two 32-kv subtiles, k=d in 4 steps of 16
        f32x16 s0 = zero16(), s1 = zero16();
#pragma unroll
        for (int sd = 0; sd < 4; ++sd) {
            const bf16x8 kf0 = *(const bf16x8*)&Ks[lq * KST + sd * 16 + hi * 8];
            const bf16x8 kf1 = *(const bf16x8*)&Ks[(32 + lq) * KST + sd * 16 + hi * 8];
            s0 = __builtin_amdgcn_mfma_f32_32x32x16_bf16(kf0, qf[sd], s0, 0, 0, 0);
            s1 = __builtin_amdgcn_mfma_f32_32x32x16_bf16(kf1, qf[sd], s1, 0, 0, 0);
        }

        // per-q max over 32 in-lane values + 1 cross shuffle
        float mx;
        {
            float a = fmaxf(s0[0], s0[1]);
#pragma unroll
            for (int r = 2; r < 16; ++r) a = fmaxf(a, s0[r]);
#pragma unroll
            for (int r = 0; r < 16; ++r) a = fmaxf(a, s1[r]);
            mx = fmaxf(a, __shfl_xor(a, 32));
        }

        // defer-max: rescale only when per-tile growth exceeds 2^8
        if (!__all(mx <= m + 8.f)) {
            const float mn = fmaxf(m, mx);
            const float al = __builtin_amdgcn_exp2f(m - mn);
            m = mn;
#pragma unroll
            for (int r = 0; r < 16; ++r) { o0[r] *= al; o1[r] *= al; }
            lacc[0] *= al;
        }

        // P = exp2(S^T - m)
        float p0[16], p1[16];
#pragma unroll
        for (int r = 0; r < 16; ++r) p0[r] = __builtin_amdgcn_exp2f(s0[r] - m);
#pragma unroll
        for (int r = 0; r < 16; ++r) p1[r] = __builtin_amdgcn_exp2f(s1[r] - m);

        // per 16-k window w: pack 8 values, exchange halves, feed PV + l MFMAs
#pragma unroll
        for (int w = 0; w < 4; ++w) {
            const int rb = (w & 1) * 8;
            unsigned w0, w1, w2, w3;
            if (w < 2) {
                w0 = pk2(p0[rb + 0], p0[rb + 1]); w1 = pk2(p0[rb + 2], p0[rb + 3]);
                w2 = pk2(p0[rb + 4], p0[rb + 5]); w3 = pk2(p0[rb + 6], p0[rb + 7]);
            } else {
                w0 = pk2(p1[rb + 0], p1[rb + 1]); w1 = pk2(p1[rb + 2], p1[rb + 3]);
                w2 = pk2(p1[rb + 4], p1[rb + 5]); w3 = pk2(p1[rb + 6], p1[rb + 7]);
            }
            // hi=0 holds r=16w+{0-3,8-11}, needs {0-7}; hi=1 holds {4-7,12-15}, needs {8-15}
            const unsigned send0 = hi ? w0 : w2;
            const unsigned send1 = hi ? w1 : w3;
            const unsigned recv0 = __shfl_xor(send0, 32);
            const unsigned recv1 = __shfl_xor(send1, 32);
            union { unsigned u[4]; bf16x8 v; } pf;
            pf.u[0] = hi ? recv0 : w0;
            pf.u[1] = hi ? recv1 : w1;
            pf.u[2] = hi ? w2 : recv0;
            pf.u[3] = hi ? w3 : recv1;

            const bf16x8 vf0 = *(const bf16x8*)&Vs[lq * KST + w * 16 + hi * 8];
            const bf16x8 vf1 = *(const bf16x8*)&Vs[(32 + lq) * KST + w * 16 + hi * 8];
            o0   = __builtin_amdgcn_mfma_f32_32x32x16_bf16(vf0, pf.v, o0, 0, 0, 0);
            o1   = __builtin_amdgcn_mfma_f32_32x32x16_bf16(vf1, pf.v, o1, 0, 0, 0);
            lacc = __builtin_amdgcn_mfma_f32_32x32x16_bf16(ones, pf.v, lacc, 0, 0, 0);
        }
    }

    // epilogue: O^T[d][q] regs -> Ob[q][h*64+d], normalize by l
    const float inv = 1.0f / lacc[0];
    __bf16* obase = &Ob[qrow * E_DIM + h * HD];
#pragma unroll
    for (int grp = 0; grp < 4; ++grp) {
        bf16x4 v0, v1;
#pragma unroll
        for (int c = 0; c < 4; ++c) {
            v0[c] = (__bf16)(o0[grp * 4 + c] * inv);
            v1[c] = (__bf16)(o1[grp * 4 + c] * inv);
        }
        *(bf16x4*)&obase[grp * 8 + hi * 4]      = v0;
        *(bf16x4*)&obase[32 + grp * 8 + hi * 4] = v1;
    }
}

// ---------- kernel 3: output projection ----------
__global__ __launch_bounds__(256) void proj_gemm(const __bf16* __restrict__ Ob,
                                                 const float* __restrict__ wp,
                                                 const float* __restrict__ bp,
                                                 float* __restrict__ out) {
    __shared__ __bf16 As[128 * LDSTR];
    __shared__ __bf16 Bs[128 * LDSTR];
    f32x4 acc[4][4];
#pragma unroll
    for (int i = 0; i < 4; ++i)
#pragma unroll
        for (int j = 0; j < 4; ++j)
            acc[i][j] = f32x4{0.f, 0.f, 0.f, 0.f};

    const int tm = blockIdx.x, tn = blockIdx.y;
    gemm_core(Ob, wp, E_DIM, tm * 128, tn * 128, As, Bs, acc);

    const int tid = threadIdx.x;
    const int lane = tid & 63, wid = tid >> 6;
    const int wm = wid >> 1, wn = wid & 1;
    const int lr = lane & 15, lg = lane >> 4;

#pragma unroll
    for (int ni = 0; ni < 4; ++ni) {
        const int f = tn * 128 + wn * 64 + ni * 16 + lr;
        const float bias = bp[f];
#pragma unroll
        for (int mi = 0; mi < 4; ++mi) {
#pragma unroll
            for (int r = 0; r < 4; ++r) {
                const int n = tm * 128 + wm * 64 + mi * 16 + lg * 4 + r;
                out[(size_t)n * E_DIM + f] = acc[mi][ni][r] + bias;
            }
        }
    }
}

// ---------- launch ----------
extern "C" void kernel_launch(void* const* d_in, const int* in_sizes, int n_in,
                              void* d_out, int out_size, void* d_ws, size_t ws_size,
                              hipStream_t stream) {
    const float* x     = (const float*)d_in[0];
    const float* wqkv  = (const float*)d_in[1];
    const float* bqkv  = (const float*)d_in[2];
    const float* wproj = (const float*)d_in[3];
    const float* bproj = (const float*)d_in[4];
    float* out = (float*)d_out;

    const size_t headElems = (size_t)NH * N_TOK * HD;   // 4M elems
    __bf16* Qb  = (__bf16*)d_ws;
    __bf16* Kb  = Qb + headElems;
    __bf16* VtG = Kb + headElems;                       // [H][D][N]
    __bf16* Ob  = VtG + headElems;                      // [N][E] bf16

    qkv_gemm<<<dim3(N_TOK / 128, 3 * E_DIM / 128), 256, 0, stream>>>(x, wqkv, bqkv, Qb, Kb, VtG);
    flash_attn<<<dim3(N_TOK / QBLK, NH), 256, 0, stream>>>(Qb, Kb, VtG, Ob);
    proj_gemm<<<dim3(N_TOK / 128, E_DIM / 128), 256, 0, stream>>>(Ob, wproj, bproj, out);
}

// Round 5
// 192.906 us; speedup vs baseline: 2.2711x; 1.1001x over previous
//
#include <hip/hip_runtime.h>

#define N_TOK 4096
#define E_DIM 1024
#define NH    16
#define HD    64

typedef __bf16 bf16x8 __attribute__((ext_vector_type(8)));
typedef __bf16 bf16x4 __attribute__((ext_vector_type(4)));
typedef float  f32x4  __attribute__((ext_vector_type(4)));
typedef float  f32x16 __attribute__((ext_vector_type(16)));

#define GLOAD16(gsrc, ldst) __builtin_amdgcn_global_load_lds( \
    (const __attribute__((address_space(1))) void*)(gsrc),    \
    (__attribute__((address_space(3))) void*)(ldst), 16, 0, 0)

__device__ __forceinline__ f32x16 zero16() {
    f32x16 z;
#pragma unroll
    for (int i = 0; i < 16; ++i) z[i] = 0.f;
    return z;
}

__device__ __forceinline__ unsigned pk2(float a, float b) {
    union { __bf16 h[2]; unsigned u; } t;
    t.h[0] = (__bf16)a; t.h[1] = (__bf16)b;
    return t.u;
}

__device__ __forceinline__ void load16(const __bf16* __restrict__ p, bf16x8& lo, bf16x8& hi) {
    lo = *(const bf16x8*)p;
    hi = *(const bf16x8*)(p + 8);
}

// ---------- kernel 0: fp32 -> bf16 convert (memory-bound) ----------
__global__ __launch_bounds__(256) void conv_bf16(const float* __restrict__ src,
                                                 __bf16* __restrict__ dst, int n8) {
    const int i = blockIdx.x * 256 + threadIdx.x;
    if (i >= n8) return;
    const float4 a = ((const float4*)src)[i * 2];
    const float4 b = ((const float4*)src)[i * 2 + 1];
    ((bf16x8*)dst)[i] = bf16x8{(__bf16)a.x, (__bf16)a.y, (__bf16)a.z, (__bf16)a.w,
                               (__bf16)b.x, (__bf16)b.y, (__bf16)b.z, (__bf16)b.w};
}

// ---------- shared GEMM core (m97 structure): 128x128 tile, BK=32, global_load_lds ----------
// out[n][f] = sum_k A[n][k]*B[f][k]; A,B bf16 row-major K-contiguous. LDS linear [128][32].
__device__ __forceinline__ void gemm_core(const __bf16* __restrict__ A, const __bf16* __restrict__ B,
                                          const int K, const int rowBase, const int colBase,
                                          __bf16* As, __bf16* Bs, f32x4 (&acc)[4][4]) {
    const int tid = threadIdx.x, lane = tid & 63, wid = tid >> 6;
    const int wm = wid >> 1, wn = wid & 1;
    const int lr = lane & 15, lg = lane >> 4;
    const int lrow = lane >> 2, lcol = (lane & 3) * 8;

    const __bf16* aBase = A + (size_t)(rowBase + wid * 16 + lrow) * K + lcol;
    const __bf16* bBase = B + (size_t)(colBase + wid * 16 + lrow) * K + lcol;
    const size_t row64 = (size_t)64 * K;

    for (int kt = 0; kt < K; kt += 32) {
        __syncthreads();   // readers of previous tile done
        GLOAD16(aBase + kt,         As + wid * 512);
        GLOAD16(aBase + row64 + kt, As + 2048 + wid * 512);
        GLOAD16(bBase + kt,         Bs + wid * 512);
        GLOAD16(bBase + row64 + kt, Bs + 2048 + wid * 512);
        __syncthreads();   // vmcnt drained -> tile visible

        bf16x8 af[4], bfr[4];
#pragma unroll
        for (int i = 0; i < 4; ++i) {
            af[i]  = *(const bf16x8*)&As[(wm * 64 + i * 16 + lr) * 32 + lg * 8];
            bfr[i] = *(const bf16x8*)&Bs[(wn * 64 + i * 16 + lr) * 32 + lg * 8];
        }
#pragma unroll
        for (int i = 0; i < 4; ++i)
#pragma unroll
            for (int j = 0; j < 4; ++j)
                acc[i][j] = __builtin_amdgcn_mfma_f32_16x16x32_bf16(af[i], bfr[j], acc[i][j], 0, 0, 0);
    }
}

// ---------- kernel 1: QKV projection; Q,K row-major [h][n][d], V transposed [h][d][n] ----------
#define QSCALE 0.180336879f   // 1/sqrt(64) * log2(e)

__global__ __launch_bounds__(256) void qkv_gemm(const __bf16* __restrict__ x,
                                                const __bf16* __restrict__ wqkv,
                                                const float* __restrict__ bqkv,
                                                __bf16* __restrict__ Qb,
                                                __bf16* __restrict__ Kb,
                                                __bf16* __restrict__ VtG) {
    __shared__ __bf16 As[128 * 32];
    __shared__ __bf16 Bs[128 * 32];
    f32x4 acc[4][4];
#pragma unroll
    for (int i = 0; i < 4; ++i)
#pragma unroll
        for (int j = 0; j < 4; ++j)
            acc[i][j] = f32x4{0.f, 0.f, 0.f, 0.f};

    const int tm = blockIdx.x, tn = blockIdx.y;
    gemm_core(x, wqkv, E_DIM, tm * 128, tn * 128, As, Bs, acc);

    const int tid = threadIdx.x;
    const int lane = tid & 63, wid = tid >> 6;
    const int wm = wid >> 1, wn = wid & 1;
    const int lr = lane & 15, lg = lane >> 4;

#pragma unroll
    for (int ni = 0; ni < 4; ++ni) {
        const int f = tn * 128 + wn * 64 + ni * 16 + lr;   // 0..3071
        const float bias = bqkv[f];
        const int which = f >> 10;          // 0=Q 1=K 2=V (uniform per block)
        const int hh = (f & 1023) >> 6;
        const int dd = f & 63;
        if (which == 2) {
            __bf16* dst = VtG + ((size_t)hh * HD + dd) * N_TOK;
#pragma unroll
            for (int mi = 0; mi < 4; ++mi) {
                const int n0 = tm * 128 + wm * 64 + mi * 16 + lg * 4;
                bf16x4 v;
#pragma unroll
                for (int r = 0; r < 4; ++r) v[r] = (__bf16)(acc[mi][ni][r] + bias);
                *(bf16x4*)&dst[n0] = v;
            }
        } else {
            __bf16* dst = (which == 0) ? Qb : Kb;
            const float sc = (which == 0) ? QSCALE : 1.0f;
#pragma unroll
            for (int mi = 0; mi < 4; ++mi) {
#pragma unroll
                for (int r = 0; r < 4; ++r) {
                    const int n = tm * 128 + wm * 64 + mi * 16 + lg * 4 + r;
                    dst[((size_t)hh * N_TOK + n) * HD + dd] = (__bf16)((acc[mi][ni][r] + bias) * sc);
                }
            }
        }
    }
}

// ---------- kernel 2: flash attention, 8 waves, kv-split pairs, dbuf single-barrier ----------
// grid (32 qblocks, 16 heads), 512 threads = 8 waves. Wave wid: q-group wid>>1 (32 q rows),
// kv-half wid&1 (64 of each 128-kv tile). Independent online softmax per wave; merged via LDS.
#define QBLK  128
#define KVB   128
#define NTILE (N_TOK / KVB)
#define KST   72    // K LDS stride [kv][d]
#define VST   136   // V LDS stride [d][kv]
#define BUFSZ (KVB * KST + HD * VST)

__global__ __launch_bounds__(512, 4) void flash_attn(const __bf16* __restrict__ Qb,
                                                     const __bf16* __restrict__ Kb,
                                                     const __bf16* __restrict__ Vt,
                                                     __bf16* __restrict__ Ob) {
    __shared__ __bf16 smem[2 * BUFSZ];   // 71680 B

    const int qblk = blockIdx.x, h = blockIdx.y;
    const int tid = threadIdx.x, lane = tid & 63, wid = tid >> 6;
    const int lq = lane & 31, hi = lane >> 5;
    const int qg = wid >> 1, hw = wid & 1;

    const __bf16* Qh = Qb + (size_t)h * N_TOK * HD;
    const __bf16* Kh = Kb + (size_t)h * N_TOK * HD;
    const __bf16* Vh = Vt + (size_t)h * HD * N_TOK;

    // Q B-frags: col=q=lq, k-slot (hi,j): d = sd*16 + hi*8 + j
    const size_t qrow = (size_t)qblk * QBLK + qg * 32 + lq;
    bf16x8 qf[4];
#pragma unroll
    for (int sd = 0; sd < 4; ++sd)
        qf[sd] = *(const bf16x8*)&Qh[qrow * HD + sd * 16 + hi * 8];

    f32x16 o0 = zero16(), o1 = zero16(), lacc = zero16();
    float m = -INFINITY;

    const bf16x8 ones = bf16x8{(__bf16)1.f, (__bf16)1.f, (__bf16)1.f, (__bf16)1.f,
                               (__bf16)1.f, (__bf16)1.f, (__bf16)1.f, (__bf16)1.f};

    // staging: K tile 128x64 (4 thr/row), V tile 64x128 (8 thr/row)
    const int krow = tid >> 2, kseg = (tid & 3) * 16;
    const int vrow = tid >> 3, vseg = (tid & 7) * 16;
    const __bf16* kSrc = Kh + (size_t)krow * HD + kseg;
    const __bf16* vSrc = Vh + (size_t)vrow * N_TOK + vseg;

    bf16x8 kr0, kr1, vr0, vr1;
    load16(kSrc, kr0, kr1);
    load16(vSrc, vr0, vr1);
    {   // prologue: write tile 0 into buf 0
        __bf16* Kw = smem;
        __bf16* Vw = smem + KVB * KST;
        *(bf16x8*)&Kw[krow * KST + kseg]     = kr0;
        *(bf16x8*)&Kw[krow * KST + kseg + 8] = kr1;
        *(bf16x8*)&Vw[vrow * VST + vseg]     = vr0;
        *(bf16x8*)&Vw[vrow * VST + vseg + 8] = vr1;
    }

    for (int t = 0; t < NTILE; ++t) {
        const int cur = t & 1;
        const __bf16* Kc = smem + cur * BUFSZ;
        const __bf16* Vc = Kc + KVB * KST;

        if (t + 1 < NTILE) {   // prefetch next tile into regs
            load16(kSrc + (size_t)(t + 1) * KVB * HD, kr0, kr1);
            load16(vSrc + (t + 1) * KVB, vr0, vr1);
        }
        __syncthreads();   // buf[cur] visible; buf[cur^1] readers (tile t-1) done

        // S^T = K Q^T on this wave's 64-kv half
        f32x16 s0 = zero16(), s1 = zero16();
        __builtin_amdgcn_s_setprio(1);
#pragma unroll
        for (int sd = 0; sd < 4; ++sd) {
            const bf16x8 kf0 = *(const bf16x8*)&Kc[(hw * 64 + lq) * KST + sd * 16 + hi * 8];
            const bf16x8 kf1 = *(const bf16x8*)&Kc[(hw * 64 + 32 + lq) * KST + sd * 16 + hi * 8];
            s0 = __builtin_amdgcn_mfma_f32_32x32x16_bf16(kf0, qf[sd], s0, 0, 0, 0);
            s1 = __builtin_amdgcn_mfma_f32_32x32x16_bf16(kf1, qf[sd], s1, 0, 0, 0);
        }
        __builtin_amdgcn_s_setprio(0);

        // tree max over the 32 in-lane S values + cross-half shuffle
        float mx;
        {
            const float t0 = fmaxf(fmaxf(s0[0], s0[1]),  fmaxf(s0[2], s0[3]));
            const float t1 = fmaxf(fmaxf(s0[4], s0[5]),  fmaxf(s0[6], s0[7]));
            const float t2 = fmaxf(fmaxf(s0[8], s0[9]),  fmaxf(s0[10], s0[11]));
            const float t3 = fmaxf(fmaxf(s0[12], s0[13]), fmaxf(s0[14], s0[15]));
            const float t4 = fmaxf(fmaxf(s1[0], s1[1]),  fmaxf(s1[2], s1[3]));
            const float t5 = fmaxf(fmaxf(s1[4], s1[5]),  fmaxf(s1[6], s1[7]));
            const float t6 = fmaxf(fmaxf(s1[8], s1[9]),  fmaxf(s1[10], s1[11]));
            const float t7 = fmaxf(fmaxf(s1[12], s1[13]), fmaxf(s1[14], s1[15]));
            const float u0 = fmaxf(fmaxf(t0, t1), fmaxf(t2, t3));
            const float u1 = fmaxf(fmaxf(t4, t5), fmaxf(t6, t7));
            float a = fmaxf(u0, u1);
            mx = fmaxf(a, __shfl_xor(a, 32));
        }

        // defer-max: rescale only when per-tile growth exceeds 2^8
        if (!__all(mx <= m + 8.f)) {
            const float mn = fmaxf(m, mx);
            const float al = __builtin_amdgcn_exp2f(m - mn);
            m = mn;
#pragma unroll
            for (int r = 0; r < 16; ++r) { o0[r] *= al; o1[r] *= al; }
            lacc[0] *= al;
        }

        // per 16-k window: exp2 inline, pack, cross-half exchange, 3 MFMAs
#pragma unroll
        for (int w = 0; w < 4; ++w) {
            const int rb = (w & 1) * 8;
            unsigned w0, w1, w2, w3;
            if (w < 2) {
                w0 = pk2(__builtin_amdgcn_exp2f(s0[rb + 0] - m), __builtin_amdgcn_exp2f(s0[rb + 1] - m));
                w1 = pk2(__builtin_amdgcn_exp2f(s0[rb + 2] - m), __builtin_amdgcn_exp2f(s0[rb + 3] - m));
                w2 = pk2(__builtin_amdgcn_exp2f(s0[rb + 4] - m), __builtin_amdgcn_exp2f(s0[rb + 5] - m));
                w3 = pk2(__builtin_amdgcn_exp2f(s0[rb + 6] - m), __builtin_amdgcn_exp2f(s0[rb + 7] - m));
            } else {
                w0 = pk2(__builtin_amdgcn_exp2f(s1[rb + 0] - m), __builtin_amdgcn_exp2f(s1[rb + 1] - m));
                w1 = pk2(__builtin_amdgcn_exp2f(s1[rb + 2] - m), __builtin_amdgcn_exp2f(s1[rb + 3] - m));
                w2 = pk2(__builtin_amdgcn_exp2f(s1[rb + 4] - m), __builtin_amdgcn_exp2f(s1[rb + 5] - m));
                w3 = pk2(__builtin_amdgcn_exp2f(s1[rb + 6] - m), __builtin_amdgcn_exp2f(s1[rb + 7] - m));
            }
            const unsigned send0 = hi ? w0 : w2;
            const unsigned send1 = hi ? w1 : w3;
            const unsigned recv0 = __shfl_xor(send0, 32);
            const unsigned recv1 = __shfl_xor(send1, 32);
            union { unsigned u[4]; bf16x8 v; } pf;
            pf.u[0] = hi ? recv0 : w0;
            pf.u[1] = hi ? recv1 : w1;
            pf.u[2] = hi ? w2 : recv0;
            pf.u[3] = hi ? w3 : recv1;

            const bf16x8 vf0 = *(const bf16x8*)&Vc[lq * VST + hw * 64 + w * 16 + hi * 8];
            const bf16x8 vf1 = *(const bf16x8*)&Vc[(32 + lq) * VST + hw * 64 + w * 16 + hi * 8];
            __builtin_amdgcn_s_setprio(1);
            o0   = __builtin_amdgcn_mfma_f32_32x32x16_bf16(vf0, pf.v, o0, 0, 0, 0);
            o1   = __builtin_amdgcn_mfma_f32_32x32x16_bf16(vf1, pf.v, o1, 0, 0, 0);
            lacc = __builtin_amdgcn_mfma_f32_32x32x16_bf16(ones, pf.v, lacc, 0, 0, 0);
            __builtin_amdgcn_s_setprio(0);
        }

        if (t + 1 < NTILE) {   // write prefetched tile into other buffer
            __bf16* Kw = smem + (cur ^ 1) * BUFSZ;
            __bf16* Vw = Kw + KVB * KST;
            *(bf16x8*)&Kw[krow * KST + kseg]     = kr0;
            *(bf16x8*)&Kw[krow * KST + kseg + 8] = kr1;
            *(bf16x8*)&Vw[vrow * VST + vseg]     = vr0;
            *(bf16x8*)&Vw[vrow * VST + vseg + 8] = vr1;
        }
    }

    // ---- merge kv-half pairs through LDS, then epilogue ----
    __syncthreads();   // staging LDS free
    float* scratch = (float*)smem;
    float* po  = scratch + qg * (32 * 65);            // [32 q][64 d] padded
    float* plm = scratch + 4 * (32 * 65) + qg * 64;   // [32 q][l,m]

    if (hw == 1) {
#pragma unroll
        for (int r = 0; r < 16; ++r) {
            const int d0 = (r & 3) + 8 * (r >> 2) + 4 * hi;
            po[lq * 65 + d0]      = o0[r];
            po[lq * 65 + 32 + d0] = o1[r];
        }
        if (hi == 0) { plm[lq * 2] = lacc[0]; plm[lq * 2 + 1] = m; }
    }
    __syncthreads();
    if (hw == 0) {
        const float l1 = plm[lq * 2], m1 = plm[lq * 2 + 1];
        const float M  = fmaxf(m, m1);
        const float a0 = __builtin_amdgcn_exp2f(m - M);
        const float a1 = __builtin_amdgcn_exp2f(m1 - M);
        const float inv = 1.0f / (lacc[0] * a0 + l1 * a1);
        __bf16* obase = &Ob[qrow * E_DIM + h * HD];
#pragma unroll
        for (int grp = 0; grp < 4; ++grp) {
            bf16x4 v0, v1;
#pragma unroll
            for (int c = 0; c < 4; ++c) {
                const int r = grp * 4 + c;
                const int d0 = c + 8 * grp + 4 * hi;
                v0[c] = (__bf16)((o0[r] * a0 + po[lq * 65 + d0]      * a1) * inv);
                v1[c] = (__bf16)((o1[r] * a0 + po[lq * 65 + 32 + d0] * a1) * inv);
            }
            *(bf16x4*)&obase[grp * 8 + hi * 4]      = v0;
            *(bf16x4*)&obase[32 + grp * 8 + hi * 4] = v1;
        }
    }
}

// ---------- kernel 3: output projection ----------
__global__ __launch_bounds__(256) void proj_gemm(const __bf16* __restrict__ Ob,
                                                 const __bf16* __restrict__ wp,
                                                 const float* __restrict__ bp,
                                                 float* __restrict__ out) {
    __shared__ __bf16 As[128 * 32];
    __shared__ __bf16 Bs[128 * 32];
    f32x4 acc[4][4];
#pragma unroll
    for (int i = 0; i < 4; ++i)
#pragma unroll
        for (int j = 0; j < 4; ++j)
            acc[i][j] = f32x4{0.f, 0.f, 0.f, 0.f};

    const int tm = blockIdx.x, tn = blockIdx.y;
    gemm_core(Ob, wp, E_DIM, tm * 128, tn * 128, As, Bs, acc);

    const int tid = threadIdx.x;
    const int lane = tid & 63, wid = tid >> 6;
    const int wm = wid >> 1, wn = wid & 1;
    const int lr = lane & 15, lg = lane >> 4;

#pragma unroll
    for (int ni = 0; ni < 4; ++ni) {
        const int f = tn * 128 + wn * 64 + ni * 16 + lr;
        const float bias = bp[f];
#pragma unroll
        for (int mi = 0; mi < 4; ++mi) {
#pragma unroll
            for (int r = 0; r < 4; ++r) {
                const int n = tm * 128 + wm * 64 + mi * 16 + lg * 4 + r;
                out[(size_t)n * E_DIM + f] = acc[mi][ni][r] + bias;
            }
        }
    }
}

// ---------- launch ----------
extern "C" void kernel_launch(void* const* d_in, const int* in_sizes, int n_in,
                              void* d_out, int out_size, void* d_ws, size_t ws_size,
                              hipStream_t stream) {
    const float* x     = (const float*)d_in[0];
    const float* wqkv  = (const float*)d_in[1];
    const float* bqkv  = (const float*)d_in[2];
    const float* wproj = (const float*)d_in[3];
    const float* bproj = (const float*)d_in[4];
    float* out = (float*)d_out;

    const size_t headElems = (size_t)NH * N_TOK * HD;      // 4.19M
    __bf16* Qb   = (__bf16*)d_ws;
    __bf16* Kb   = Qb + headElems;
    __bf16* VtG  = Kb + headElems;                         // [H][D][N]
    __bf16* ObXb = VtG + headElems;                        // xb during qkv, then Ob
    __bf16* Wb   = ObXb + headElems;                       // wqkv-bf16, then wproj-bf16

    // convert inputs to bf16
    conv_bf16<<<(N_TOK * E_DIM / 8 + 255) / 256, 256, 0, stream>>>(x, ObXb, N_TOK * E_DIM / 8);
    conv_bf16<<<(3 * E_DIM * E_DIM / 8 + 255) / 256, 256, 0, stream>>>(wqkv, Wb, 3 * E_DIM * E_DIM / 8);

    qkv_gemm<<<dim3(N_TOK / 128, 3 * E_DIM / 128), 256, 0, stream>>>(ObXb, Wb, bqkv, Qb, Kb, VtG);

    conv_bf16<<<(E_DIM * E_DIM / 8 + 255) / 256, 256, 0, stream>>>(wproj, Wb, E_DIM * E_DIM / 8);

    flash_attn<<<dim3(N_TOK / QBLK, NH), 512, 0, stream>>>(Qb, Kb, VtG, ObXb);

    proj_gemm<<<dim3(N_TOK / 128, E_DIM / 128), 256, 0, stream>>>(ObXb, Wb, bproj, out);
}

// Round 6
// 189.246 us; speedup vs baseline: 2.3150x; 1.0193x over previous
//
#include <hip/hip_runtime.h>

#define N_TOK 4096
#define E_DIM 1024
#define NH    16
#define HD    64

typedef __bf16 bf16x8 __attribute__((ext_vector_type(8)));
typedef __bf16 bf16x4 __attribute__((ext_vector_type(4)));
typedef float  f32x4  __attribute__((ext_vector_type(4)));
typedef float  f32x16 __attribute__((ext_vector_type(16)));

#define GLOAD16(gsrc, ldst) __builtin_amdgcn_global_load_lds( \
    (const __attribute__((address_space(1))) void*)(gsrc),    \
    (__attribute__((address_space(3))) void*)(ldst), 16, 0, 0)

__device__ __forceinline__ f32x16 zero16() {
    f32x16 z;
#pragma unroll
    for (int i = 0; i < 16; ++i) z[i] = 0.f;
    return z;
}

__device__ __forceinline__ unsigned pk2(float a, float b) {
    union { __bf16 h[2]; unsigned u; } t;
    t.h[0] = (__bf16)a; t.h[1] = (__bf16)b;
    return t.u;
}

__device__ __forceinline__ void load16(const __bf16* __restrict__ p, bf16x8& lo, bf16x8& hi) {
    lo = *(const bf16x8*)p;
    hi = *(const bf16x8*)(p + 8);
}

// ---------- kernel 0: fp32 -> bf16 convert (memory-bound) ----------
__global__ __launch_bounds__(256) void conv_bf16(const float* __restrict__ src,
                                                 __bf16* __restrict__ dst, int n8) {
    const int i = blockIdx.x * 256 + threadIdx.x;
    if (i >= n8) return;
    const float4 a = ((const float4*)src)[i * 2];
    const float4 b = ((const float4*)src)[i * 2 + 1];
    ((bf16x8*)dst)[i] = bf16x8{(__bf16)a.x, (__bf16)a.y, (__bf16)a.z, (__bf16)a.w,
                               (__bf16)b.x, (__bf16)b.y, (__bf16)b.z, (__bf16)b.w};
}

// ---------- shared GEMM core (m97 structure): 128x128 tile, BK=32, global_load_lds ----------
__device__ __forceinline__ void gemm_core(const __bf16* __restrict__ A, const __bf16* __restrict__ B,
                                          const int K, const int rowBase, const int colBase,
                                          __bf16* As, __bf16* Bs, f32x4 (&acc)[4][4]) {
    const int tid = threadIdx.x, lane = tid & 63, wid = tid >> 6;
    const int wm = wid >> 1, wn = wid & 1;
    const int lr = lane & 15, lg = lane >> 4;
    const int lrow = lane >> 2, lcol = (lane & 3) * 8;

    const __bf16* aBase = A + (size_t)(rowBase + wid * 16 + lrow) * K + lcol;
    const __bf16* bBase = B + (size_t)(colBase + wid * 16 + lrow) * K + lcol;
    const size_t row64 = (size_t)64 * K;

    for (int kt = 0; kt < K; kt += 32) {
        __syncthreads();
        GLOAD16(aBase + kt,         As + wid * 512);
        GLOAD16(aBase + row64 + kt, As + 2048 + wid * 512);
        GLOAD16(bBase + kt,         Bs + wid * 512);
        GLOAD16(bBase + row64 + kt, Bs + 2048 + wid * 512);
        __syncthreads();

        bf16x8 af[4], bfr[4];
#pragma unroll
        for (int i = 0; i < 4; ++i) {
            af[i]  = *(const bf16x8*)&As[(wm * 64 + i * 16 + lr) * 32 + lg * 8];
            bfr[i] = *(const bf16x8*)&Bs[(wn * 64 + i * 16 + lr) * 32 + lg * 8];
        }
#pragma unroll
        for (int i = 0; i < 4; ++i)
#pragma unroll
            for (int j = 0; j < 4; ++j)
                acc[i][j] = __builtin_amdgcn_mfma_f32_16x16x32_bf16(af[i], bfr[j], acc[i][j], 0, 0, 0);
    }
}

// ---------- kernel 1: QKV projection; Q,K row-major [h][n][d], V transposed [h][d][n] ----------
#define QSCALE 0.180336879f   // 1/sqrt(64) * log2(e)

__global__ __launch_bounds__(256) void qkv_gemm(const __bf16* __restrict__ x,
                                                const __bf16* __restrict__ wqkv,
                                                const float* __restrict__ bqkv,
                                                __bf16* __restrict__ Qb,
                                                __bf16* __restrict__ Kb,
                                                __bf16* __restrict__ VtG) {
    __shared__ __bf16 As[128 * 32];
    __shared__ __bf16 Bs[128 * 32];
    f32x4 acc[4][4];
#pragma unroll
    for (int i = 0; i < 4; ++i)
#pragma unroll
        for (int j = 0; j < 4; ++j)
            acc[i][j] = f32x4{0.f, 0.f, 0.f, 0.f};

    // XCD-aware swizzle: 768 blocks, 96/XCD chunk -> B-panel L2 reuse
    const int lin = blockIdx.y * 32 + blockIdx.x;
    const int swz = (lin & 7) * 96 + (lin >> 3);
    const int tm = swz & 31, tn = swz >> 5;

    gemm_core(x, wqkv, E_DIM, tm * 128, tn * 128, As, Bs, acc);

    const int tid = threadIdx.x;
    const int lane = tid & 63, wid = tid >> 6;
    const int wm = wid >> 1, wn = wid & 1;
    const int lr = lane & 15, lg = lane >> 4;

#pragma unroll
    for (int ni = 0; ni < 4; ++ni) {
        const int f = tn * 128 + wn * 64 + ni * 16 + lr;   // 0..3071
        const float bias = bqkv[f];
        const int which = f >> 10;          // 0=Q 1=K 2=V (uniform per block)
        const int hh = (f & 1023) >> 6;
        const int dd = f & 63;
        if (which == 2) {
            __bf16* dst = VtG + ((size_t)hh * HD + dd) * N_TOK;
#pragma unroll
            for (int mi = 0; mi < 4; ++mi) {
                const int n0 = tm * 128 + wm * 64 + mi * 16 + lg * 4;
                bf16x4 v;
#pragma unroll
                for (int r = 0; r < 4; ++r) v[r] = (__bf16)(acc[mi][ni][r] + bias);
                *(bf16x4*)&dst[n0] = v;
            }
        } else {
            __bf16* dst = (which == 0) ? Qb : Kb;
            const float sc = (which == 0) ? QSCALE : 1.0f;
#pragma unroll
            for (int mi = 0; mi < 4; ++mi) {
#pragma unroll
                for (int r = 0; r < 4; ++r) {
                    const int n = tm * 128 + wm * 64 + mi * 16 + lg * 4 + r;
                    dst[((size_t)hh * N_TOK + n) * HD + dd] = (__bf16)((acc[mi][ni][r] + bias) * sc);
                }
            }
        }
    }
}

// ---------- kernel 2: flash attention, 8 waves, kv-split pairs, swizzled LDS dbuf ----------
// K LDS: [128 kv][64 d] bf16 (128B rows); V LDS: [64 d][128 kv] (256B rows).
// Byte addr XOR-swizzle ((row&7)<<4) on BOTH write and read sides (T2).
#define QBLK  128
#define KVB   128
#define NTILE (N_TOK / KVB)
#define KBYTES 16384
#define BUFB   32768

__device__ __forceinline__ int kaddr(int r, int cb) { return r * 128 + (cb ^ ((r & 7) << 4)); }
__device__ __forceinline__ int vaddr(int r, int cb) { return r * 256 + (cb ^ ((r & 7) << 4)); }

__global__ __launch_bounds__(512, 2) void flash_attn(const __bf16* __restrict__ Qb,
                                                     const __bf16* __restrict__ Kb,
                                                     const __bf16* __restrict__ Vt,
                                                     __bf16* __restrict__ Ob) {
    __shared__ char smem[2 * BUFB];   // 64 KiB

    const int tid = threadIdx.x, lane = tid & 63, wid = tid >> 6;
    const int lq = lane & 31, hi = lane >> 5;
    const int qg = wid >> 1, hw = wid & 1;

    // XCD swizzle: 512 blocks, 64/XCD = 2 full heads' K/V resident per XCD L2
    const int lin = blockIdx.y * 32 + blockIdx.x;
    const int swz = (lin & 7) * 64 + (lin >> 3);
    const int qblk = swz & 31, h = swz >> 5;

    const __bf16* Qh = Qb + (size_t)h * N_TOK * HD;
    const __bf16* Kh = Kb + (size_t)h * N_TOK * HD;
    const __bf16* Vh = Vt + (size_t)h * HD * N_TOK;

    // Q B-frags: col=q=lq, k-slot (hi,j): d = sd*16 + hi*8 + j
    const size_t qrow = (size_t)qblk * QBLK + qg * 32 + lq;
    bf16x8 qf[4];
#pragma unroll
    for (int sd = 0; sd < 4; ++sd)
        qf[sd] = *(const bf16x8*)&Qh[qrow * HD + sd * 16 + hi * 8];

    f32x16 o0 = zero16(), o1 = zero16(), lacc = zero16();
    float m = -INFINITY;

    const bf16x8 ones = bf16x8{(__bf16)1.f, (__bf16)1.f, (__bf16)1.f, (__bf16)1.f,
                               (__bf16)1.f, (__bf16)1.f, (__bf16)1.f, (__bf16)1.f};

    // staging: K tile 128x64 (4 thr/row), V tile 64x128 (8 thr/row)
    const int krow = tid >> 2, kByte = (tid & 3) * 32;
    const int vrow = tid >> 3, vByte = (tid & 7) * 32;
    const __bf16* kSrc = Kh + (size_t)krow * HD + (kByte >> 1);
    const __bf16* vSrc = Vh + (size_t)vrow * N_TOK + (vByte >> 1);
    const int kw0 = kaddr(krow, kByte), kw1 = kaddr(krow, kByte + 16);
    const int vw0 = vaddr(vrow, vByte), vw1 = vaddr(vrow, vByte + 16);

    bf16x8 kr0, kr1, vr0, vr1;
    load16(kSrc, kr0, kr1);
    load16(vSrc, vr0, vr1);
    {   // prologue: tile 0 -> buf 0
        *(bf16x8*)(smem + kw0) = kr0;
        *(bf16x8*)(smem + kw1) = kr1;
        *(bf16x8*)(smem + KBYTES + vw0) = vr0;
        *(bf16x8*)(smem + KBYTES + vw1) = vr1;
    }

    for (int t = 0; t < NTILE; ++t) {
        const int cur = t & 1;
        const char* Kc = smem + cur * BUFB;
        const char* Vc = Kc + KBYTES;

        if (t + 1 < NTILE) {   // prefetch next tile into regs (hides HBM under compute)
            load16(kSrc + (size_t)(t + 1) * KVB * HD, kr0, kr1);
            load16(vSrc + (t + 1) * KVB, vr0, vr1);
        }
        __syncthreads();   // buf[cur] visible; buf[cur^1] readers done

        // S^T = K Q^T on this wave's 64-kv half
        f32x16 s0 = zero16(), s1 = zero16();
        __builtin_amdgcn_s_setprio(1);
#pragma unroll
        for (int sd = 0; sd < 4; ++sd) {
            const bf16x8 kf0 = *(const bf16x8*)(Kc + kaddr(hw * 64 + lq,      sd * 32 + hi * 16));
            const bf16x8 kf1 = *(const bf16x8*)(Kc + kaddr(hw * 64 + 32 + lq, sd * 32 + hi * 16));
            s0 = __builtin_amdgcn_mfma_f32_32x32x16_bf16(kf0, qf[sd], s0, 0, 0, 0);
            s1 = __builtin_amdgcn_mfma_f32_32x32x16_bf16(kf1, qf[sd], s1, 0, 0, 0);
        }
        __builtin_amdgcn_s_setprio(0);

        // tree max over 32 in-lane S values + cross-half shuffle
        float mx;
        {
            const float t0 = fmaxf(fmaxf(s0[0], s0[1]),  fmaxf(s0[2], s0[3]));
            const float t1 = fmaxf(fmaxf(s0[4], s0[5]),  fmaxf(s0[6], s0[7]));
            const float t2 = fmaxf(fmaxf(s0[8], s0[9]),  fmaxf(s0[10], s0[11]));
            const float t3 = fmaxf(fmaxf(s0[12], s0[13]), fmaxf(s0[14], s0[15]));
            const float t4 = fmaxf(fmaxf(s1[0], s1[1]),  fmaxf(s1[2], s1[3]));
            const float t5 = fmaxf(fmaxf(s1[4], s1[5]),  fmaxf(s1[6], s1[7]));
            const float t6 = fmaxf(fmaxf(s1[8], s1[9]),  fmaxf(s1[10], s1[11]));
            const float t7 = fmaxf(fmaxf(s1[12], s1[13]), fmaxf(s1[14], s1[15]));
            const float u0 = fmaxf(fmaxf(t0, t1), fmaxf(t2, t3));
            const float u1 = fmaxf(fmaxf(t4, t5), fmaxf(t6, t7));
            float a = fmaxf(u0, u1);
            mx = fmaxf(a, __shfl_xor(a, 32));
        }

        // defer-max: rescale only when per-tile growth exceeds 2^8
        if (!__all(mx <= m + 8.f)) {
            const float mn = fmaxf(m, mx);
            const float al = __builtin_amdgcn_exp2f(m - mn);
            m = mn;
#pragma unroll
            for (int r = 0; r < 16; ++r) { o0[r] *= al; o1[r] *= al; }
            lacc[0] *= al;
        }

        // per 16-k window: exp2 inline, pack, cross-half exchange, 3 MFMAs
#pragma unroll
        for (int w = 0; w < 4; ++w) {
            const int rb = (w & 1) * 8;
            unsigned w0, w1, w2, w3;
            if (w < 2) {
                w0 = pk2(__builtin_amdgcn_exp2f(s0[rb + 0] - m), __builtin_amdgcn_exp2f(s0[rb + 1] - m));
                w1 = pk2(__builtin_amdgcn_exp2f(s0[rb + 2] - m), __builtin_amdgcn_exp2f(s0[rb + 3] - m));
                w2 = pk2(__builtin_amdgcn_exp2f(s0[rb + 4] - m), __builtin_amdgcn_exp2f(s0[rb + 5] - m));
                w3 = pk2(__builtin_amdgcn_exp2f(s0[rb + 6] - m), __builtin_amdgcn_exp2f(s0[rb + 7] - m));
            } else {
                w0 = pk2(__builtin_amdgcn_exp2f(s1[rb + 0] - m), __builtin_amdgcn_exp2f(s1[rb + 1] - m));
                w1 = pk2(__builtin_amdgcn_exp2f(s1[rb + 2] - m), __builtin_amdgcn_exp2f(s1[rb + 3] - m));
                w2 = pk2(__builtin_amdgcn_exp2f(s1[rb + 4] - m), __builtin_amdgcn_exp2f(s1[rb + 5] - m));
                w3 = pk2(__builtin_amdgcn_exp2f(s1[rb + 6] - m), __builtin_amdgcn_exp2f(s1[rb + 7] - m));
            }
            const unsigned send0 = hi ? w0 : w2;
            const unsigned send1 = hi ? w1 : w3;
            const unsigned recv0 = __shfl_xor(send0, 32);
            const unsigned recv1 = __shfl_xor(send1, 32);
            union { unsigned u[4]; bf16x8 v; } pf;
            pf.u[0] = hi ? recv0 : w0;
            pf.u[1] = hi ? recv1 : w1;
            pf.u[2] = hi ? w2 : recv0;
            pf.u[3] = hi ? w3 : recv1;

            const bf16x8 vf0 = *(const bf16x8*)(Vc + vaddr(lq,      hw * 128 + w * 32 + hi * 16));
            const bf16x8 vf1 = *(const bf16x8*)(Vc + vaddr(32 + lq, hw * 128 + w * 32 + hi * 16));
            __builtin_amdgcn_s_setprio(1);
            o0   = __builtin_amdgcn_mfma_f32_32x32x16_bf16(vf0, pf.v, o0, 0, 0, 0);
            o1   = __builtin_amdgcn_mfma_f32_32x32x16_bf16(vf1, pf.v, o1, 0, 0, 0);
            lacc = __builtin_amdgcn_mfma_f32_32x32x16_bf16(ones, pf.v, lacc, 0, 0, 0);
            __builtin_amdgcn_s_setprio(0);
        }

        if (t + 1 < NTILE) {   // write prefetched tile into other buffer
            char* Kw = smem + (cur ^ 1) * BUFB;
            *(bf16x8*)(Kw + kw0) = kr0;
            *(bf16x8*)(Kw + kw1) = kr1;
            *(bf16x8*)(Kw + KBYTES + vw0) = vr0;
            *(bf16x8*)(Kw + KBYTES + vw1) = vr1;
        }
    }

    // ---- merge kv-half pairs through LDS, then epilogue ----
    __syncthreads();
    float* scratch = (float*)smem;
    float* po  = scratch + qg * (32 * 65);            // [32 q][64 d] padded
    float* plm = scratch + 4 * (32 * 65) + qg * 64;   // [32 q][l,m]

    if (hw == 1) {
#pragma unroll
        for (int r = 0; r < 16; ++r) {
            const int d0 = (r & 3) + 8 * (r >> 2) + 4 * hi;
            po[lq * 65 + d0]      = o0[r];
            po[lq * 65 + 32 + d0] = o1[r];
        }
        if (hi == 0) { plm[lq * 2] = lacc[0]; plm[lq * 2 + 1] = m; }
    }
    __syncthreads();
    if (hw == 0) {
        const float l1 = plm[lq * 2], m1 = plm[lq * 2 + 1];
        const float M  = fmaxf(m, m1);
        const float a0 = __builtin_amdgcn_exp2f(m - M);
        const float a1 = __builtin_amdgcn_exp2f(m1 - M);
        const float inv = 1.0f / (lacc[0] * a0 + l1 * a1);
        __bf16* obase = &Ob[qrow * E_DIM + h * HD];
#pragma unroll
        for (int grp = 0; grp < 4; ++grp) {
            bf16x4 v0, v1;
#pragma unroll
            for (int c = 0; c < 4; ++c) {
                const int r = grp * 4 + c;
                const int d0 = c + 8 * grp + 4 * hi;
                v0[c] = (__bf16)((o0[r] * a0 + po[lq * 65 + d0]      * a1) * inv);
                v1[c] = (__bf16)((o1[r] * a0 + po[lq * 65 + 32 + d0] * a1) * inv);
            }
            *(bf16x4*)&obase[grp * 8 + hi * 4]      = v0;
            *(bf16x4*)&obase[32 + grp * 8 + hi * 4] = v1;
        }
    }
}

// ---------- kernel 3: output projection ----------
__global__ __launch_bounds__(256) void proj_gemm(const __bf16* __restrict__ Ob,
                                                 const __bf16* __restrict__ wp,
                                                 const float* __restrict__ bp,
                                                 float* __restrict__ out) {
    __shared__ __bf16 As[128 * 32];
    __shared__ __bf16 Bs[128 * 32];
    f32x4 acc[4][4];
#pragma unroll
    for (int i = 0; i < 4; ++i)
#pragma unroll
        for (int j = 0; j < 4; ++j)
            acc[i][j] = f32x4{0.f, 0.f, 0.f, 0.f};

    // XCD swizzle: 256 blocks, 32/XCD = one full B-panel row per XCD
    const int lin = blockIdx.y * 32 + blockIdx.x;
    const int swz = (lin & 7) * 32 + (lin >> 3);
    const int tm = swz & 31, tn = swz >> 5;

    gemm_core(Ob, wp, E_DIM, tm * 128, tn * 128, As, Bs, acc);

    const int tid = threadIdx.x;
    const int lane = tid & 63, wid = tid >> 6;
    const int wm = wid >> 1, wn = wid & 1;
    const int lr = lane & 15, lg = lane >> 4;

#pragma unroll
    for (int ni = 0; ni < 4; ++ni) {
        const int f = tn * 128 + wn * 64 + ni * 16 + lr;
        const float bias = bp[f];
#pragma unroll
        for (int mi = 0; mi < 4; ++mi) {
#pragma unroll
            for (int r = 0; r < 4; ++r) {
                const int n = tm * 128 + wm * 64 + mi * 16 + lg * 4 + r;
                out[(size_t)n * E_DIM + f] = acc[mi][ni][r] + bias;
            }
        }
    }
}

// ---------- launch ----------
extern "C" void kernel_launch(void* const* d_in, const int* in_sizes, int n_in,
                              void* d_out, int out_size, void* d_ws, size_t ws_size,
                              hipStream_t stream) {
    const float* x     = (const float*)d_in[0];
    const float* wqkv  = (const float*)d_in[1];
    const float* bqkv  = (const float*)d_in[2];
    const float* wproj = (const float*)d_in[3];
    const float* bproj = (const float*)d_in[4];
    float* out = (float*)d_out;

    const size_t headElems = (size_t)NH * N_TOK * HD;      // 4.19M
    __bf16* Qb   = (__bf16*)d_ws;
    __bf16* Kb   = Qb + headElems;
    __bf16* VtG  = Kb + headElems;                         // [H][D][N]
    __bf16* ObXb = VtG + headElems;                        // xb during qkv, then Ob
    __bf16* Wb   = ObXb + headElems;                       // wqkv-bf16, then wproj-bf16

    conv_bf16<<<(N_TOK * E_DIM / 8 + 255) / 256, 256, 0, stream>>>(x, ObXb, N_TOK * E_DIM / 8);
    conv_bf16<<<(3 * E_DIM * E_DIM / 8 + 255) / 256, 256, 0, stream>>>(wqkv, Wb, 3 * E_DIM * E_DIM / 8);

    qkv_gemm<<<dim3(N_TOK / 128, 3 * E_DIM / 128), 256, 0, stream>>>(ObXb, Wb, bqkv, Qb, Kb, VtG);

    conv_bf16<<<(E_DIM * E_DIM / 8 + 255) / 256, 256, 0, stream>>>(wproj, Wb, E_DIM * E_DIM / 8);

    flash_attn<<<dim3(N_TOK / QBLK, NH), 512, 0, stream>>>(Qb, Kb, VtG, ObXb);

    proj_gemm<<<dim3(N_TOK / 128, E_DIM / 128), 256, 0, stream>>>(ObXb, Wb, bproj, out);
}